// Round 3
// baseline (152.732 us; speedup 1.0000x reference)
//
#include <hip/hip_runtime.h>
#include <hip/hip_fp16.h>
#include <math.h>

#define BB 16
#define SS 256
#define CC 17
#define NCH 16
#define DD 32
#define DFFN 64
#define HH 4
#define DH 8
#define EE 4

// ws layout (4-byte units):
//  [8..10]     A,B,C LN1-collapse scalars
//  [16 ..143]  K0[e][d]   [144..271] V0[e][d]
//  [512..66047]  XNS[b][s][n]
//  ints at WS_SPI: SP[b][p] (4096), OFF[b][e] (64)
//  WS_WT: weight image:
//    [0,2048) WoT | [2048,6144) W1T | [6144,10240) W2T 2 planes   (staged to LDS)
//    [10240,11392) PQR f32 (3 mats x 4 e x {P[32],Q[32],R[32]})   (read from global)
#define WS_K0 16
#define WS_V0 144
#define WS_XNS 512
#define WS_SPI (WS_XNS + BB*SS*NCH)          // 66048
#define WS_WT  (WS_SPI + BB*SS + 64)         // 70208

#define PRE 0.51006977f   // (1/sqrt(8)) * log2(e)

typedef __fp16 hv2 __attribute__((ext_vector_type(2)));

__device__ __forceinline__ unsigned pkh2(float a, float b) {
  hv2 r = __builtin_amdgcn_cvt_pkrtz(a, b);
  unsigned u; __builtin_memcpy(&u, &r, 4);
  return u;
}
__device__ __forceinline__ float fd2(unsigned a, unsigned b, float c) {
  hv2 av, bv;
  __builtin_memcpy(&av, &a, 4);
  __builtin_memcpy(&bv, &b, 4);
  return __builtin_amdgcn_fdot2(av, bv, c, false);
}
__device__ __forceinline__ __half2 u2h2(unsigned u) {
  __half2 h; __builtin_memcpy(&h, &u, 4); return h;
}
template<int PAT>
__device__ __forceinline__ unsigned qdpp(unsigned v) {
  return (unsigned)__builtin_amdgcn_mov_dpp((int)v, PAT, 0xF, 0xF, true);
}
template<int PAT>
__device__ __forceinline__ float qdppf(float v) {
  return __uint_as_float(qdpp<PAT>(__float_as_uint(v)));
}

// ---------------------------------------------------------------------------
// Kernel 1 (1024 thr): decomp (blocks 0..255), prep (256..271),
// weight-image convert (272..274), LN1-collapse PQR/ABC (275).  [= R12]
// ---------------------------------------------------------------------------
__launch_bounds__(1024)
__global__ void decomp_prep_kernel(const float* __restrict__ x,
                                   const float* __restrict__ ox,
                                   const float* __restrict__ sW,
                                   const float* __restrict__ sb,
                                   const float* __restrict__ g1,
                                   const float* __restrict__ bb1,
                                   const float* __restrict__ Wq,
                                   const float* __restrict__ Wk,
                                   const float* __restrict__ Wv,
                                   const float* __restrict__ Wo,
                                   const float* __restrict__ W1,
                                   const float* __restrict__ W2,
                                   float* __restrict__ ws) {
  const int t = threadIdx.x;  // 1024
  if (blockIdx.x < 256) {
    const int b = blockIdx.x / NCH;
    const int c = blockIdx.x % NCH;
    __shared__ float xs[SS];
    __shared__ float prr[1024], pii[1024];
    __shared__ float amp[129];
    __shared__ float2 YY[129];
    __shared__ float sth;
    if (t < SS) xs[t] = x[(b*SS + t)*CC + c];
    __syncthreads();
    const float TH0 = 0.024543692606170259f;  // 2*pi/256
    {
      const int f = (t & 127) + 1;
      const int chunk = t >> 7;
      const int s0 = chunk * 32;
      const int ph0 = (f * s0) & 255;
      float si, cr; sincosf(TH0*(float)ph0, &si, &cr);
      float s1, c1; sincosf(TH0*(float)f, &s1, &c1);
      float xr = 0.f, xi = 0.f;
      #pragma unroll 4
      for (int k = 0; k < 32; ++k) {
        float xvv = xs[s0 + k];
        xr += xvv * cr;
        xi -= xvv * si;
        float nc = cr*c1 - si*s1;
        si = si*c1 + cr*s1;
        cr = nc;
      }
      prr[t] = xr; pii[t] = xi;
    }
    __syncthreads();
    if (t < 128) {
      float xr = 0.f, xi = 0.f;
      #pragma unroll
      for (int k2 = 0; k2 < 8; ++k2) { xr += prr[t + 128*k2]; xi += pii[t + 128*k2]; }
      prr[t] = xr; pii[t] = xi;
      amp[t+1] = sqrtf(xr*xr + xi*xi);
    }
    __syncthreads();
    if (t < 64) {   // wave 0: top-4 knockout
      float a0 = amp[t+1], a1 = amp[t+65];
      int i0 = t+1, i1 = t+65;
      float th = -1e30f;
      for (int r = 0; r < 4; ++r) {
        float mv = (a0 > a1) ? a0 : a1;
        int   mi = (a0 > a1) ? i0 : i1;
        for (int off = 32; off > 0; off >>= 1) {
          float ov = __shfl_xor(mv, off);
          int   oi = __shfl_xor(mi, off);
          if (ov > mv || (ov == mv && oi < mi)) { mv = ov; mi = oi; }
        }
        th = mv;
        if (mi == i0) a0 = -1e30f;
        if (mi == i1) a1 = -1e30f;
      }
      if (t == 0) sth = th;
    }
    __syncthreads();
    if (t < 128) {
      const int f = t + 1;
      float wgt = (amp[f] >= sth) ? ((f == 128) ? 1.0f : 2.0f) * (1.0f/256.0f) : 0.0f;
      YY[f] = make_float2(wgt * prr[t], wgt * pii[t]);
    }
    __syncthreads();
    {
      const int s = t & 255;
      const int fc = t >> 8;
      const int f0 = 1 + fc*32;
      const int ph0 = (s * f0) & 255;
      float si, cr; sincosf(TH0*(float)ph0, &si, &cr);
      float s1, c1; sincosf(TH0*(float)s, &s1, &c1);
      float acc = 0.f;
      #pragma unroll 4
      for (int k = 0; k < 32; ++k) {
        float2 y = YY[f0 + k];
        acc += y.x*cr - y.y*si;
        float nc = cr*c1 - si*s1;
        si = si*c1 + cr*s1;
        cr = nc;
      }
      prr[t] = acc;
    }
    __syncthreads();
    if (t < 256) {
      float season = prr[t] + prr[t+256] + prr[t+512] + prr[t+768];
      float s4 = 0.f, s8 = 0.f, s12 = 0.f;
      #pragma unroll
      for (int j = 0; j < 4; ++j)  { int p = t + j - 1; p = p < 0 ? 0 : (p > SS-1 ? SS-1 : p); s4  += xs[p]; }
      #pragma unroll
      for (int j = 0; j < 8; ++j)  { int p = t + j - 3; p = p < 0 ? 0 : (p > SS-1 ? SS-1 : p); s8  += xs[p]; }
      #pragma unroll
      for (int j = 0; j < 12; ++j) { int p = t + j - 5; p = p < 0 ? 0 : (p > SS-1 ? SS-1 : p); s12 += xs[p]; }
      float trend = (s4 * 0.25f + s8 * 0.125f + s12 * (1.0f/12.0f)) * (1.0f/3.0f);
      ws[WS_XNS + (b*SS + t)*NCH + c] = xs[t] + season + trend;
    }
  } else if (blockIdx.x < 272) {
    const int b = blockIdx.x - 256;
    __shared__ float red[32];
    __shared__ int asg[SS];
    __shared__ int cnt[EE];
    __shared__ float z0[EE*DD];
    float mn = 3e38f, mx = -3e38f;
    #pragma unroll
    for (int k = 0; k < 4; ++k) {
      float v = ox[(t + k*1024)*2 + 1];
      mn = fminf(mn, v); mx = fmaxf(mx, v);
    }
    for (int off = 32; off > 0; off >>= 1) {
      mn = fminf(mn, __shfl_xor(mn, off));
      mx = fmaxf(mx, __shfl_xor(mx, off));
    }
    if ((t & 63) == 0) { red[(t>>6)*2] = mn; red[(t>>6)*2+1] = mx; }
    __syncthreads();
    mn = red[0]; mx = red[1];
    #pragma unroll
    for (int w = 1; w < 16; ++w) { mn = fminf(mn, red[w*2]); mx = fmaxf(mx, red[w*2+1]); }
    const float step = (mx - mn) * 0.25f;
    const float e1 = mn + step, e2 = mn + 2.f*step, e3 = mn + 3.f*step;
    if (t < 256) {
      float sc = ox[(b*SS + t)*2 + 1];
      asg[t] = (sc >= e1) + (sc >= e2) + (sc >= e3);
    }
    __syncthreads();
    if (t < EE) {
      int c = 0;
      for (int s2 = 0; s2 < SS; ++s2) c += (asg[s2] == t);
      cnt[t] = c;
    }
    __syncthreads();
    int* SPw  = (int*)ws + WS_SPI;
    int* OFFw = SPw + BB*SS;
    if (t < EE) {
      int off = 0;
      for (int i = 0; i < t; ++i) off += cnt[i];
      OFFw[b*EE + t] = off;
      int kp = off;
      for (int s2 = 0; s2 < SS; ++s2) if (asg[s2] == t) SPw[b*SS + (kp++)] = s2;
    }
    if (t < 128) {
      int ee = t >> 5, d = t & 31;
      float m = 0.f;
      for (int i = 0; i < DD; ++i) m += sb[i];
      m *= (1.0f/DD);
      float var = 0.f;
      for (int i = 0; i < DD; ++i) { float df = sb[i]-m; var += df*df; }
      var *= (1.0f/DD);
      float rs = rsqrtf(var + 1e-5f);
      z0[ee*DD + d] = (sb[d]-m)*rs*g1[ee*DD+d] + bb1[ee*DD+d];
    }
    __syncthreads();
    if (b == 0 && t < 128) {
      int ee = t >> 5, d = t & 31;
      float k0 = 0.f, v0 = 0.f;
      for (int i = 0; i < DD; ++i) {
        float zz = z0[ee*DD + i];
        k0 += zz * Wk[ee*DD*DD + i*DD + d];
        v0 += zz * Wv[ee*DD*DD + i*DD + d];
      }
      ws[WS_K0 + ee*DD + d] = k0;
      ws[WS_V0 + ee*DD + d] = v0;
    }
  } else if (blockIdx.x < 275) {
    // weight-image converters: 3 blocks x 4096 slots cover [0, 10240)
    unsigned* img = (unsigned*)ws + WS_WT;
    const int base_u = (blockIdx.x - 272)*4096;
    #pragma unroll
    for (int i = 0; i < 4; ++i) {
      int u = base_u + i*1024 + t;
      if (u < 10240) {
        unsigned val;
        if (u < 2048) {                  // WoT
          int row = u >> 4, ip = u & 15;
          int e = row >> 5, qq = row & 31;
          int d = (qq & 3)*8 + (qq >> 2);
          const float* src = Wo + e*1024 + d;
          val = pkh2(src[ip*64], src[ip*64 + 32]);
        } else if (u < 6144) {           // W1T
          int r = u - 2048;
          int row = r >> 4, ip = r & 15;
          int e = row >> 6, qq = row & 63;
          int j = (qq & 3)*16 + (qq >> 2);
          const float* src = W1 + e*2048 + j;
          val = pkh2(src[ip*128], src[ip*128 + 64]);
        } else {                         // W2T (two planes)
          int r = u - 6144;
          int a = r >> 11, rr = r & 2047;
          int row = rr >> 4, ip = rr & 15;
          int e = row >> 5, qq = row & 31;
          int d = (qq & 3)*8 + (qq >> 2);
          int jp = a*16 + ip;
          const float* src = W2 + e*2048 + d;
          val = pkh2(src[2*jp*32], src[(2*jp+1)*32]);
        }
        img[u] = val;
      }
    }
  } else {
    // block 275: LN1-collapse precompute.
    __shared__ float s_a[DD], s_c[DD];
    if (t < DD) { s_a[t] = sW[t]; s_c[t] = sb[t]; }
    __syncthreads();
    if (t == 0) {
      float mW = 0.f, mb = 0.f;
      for (int d = 0; d < DD; ++d) { mW += s_a[d]; mb += s_c[d]; }
      mW *= (1.0f/DD); mb *= (1.0f/DD);
      float A = 0.f, Bv = 0.f, Cv = 0.f;
      for (int d = 0; d < DD; ++d) {
        float a = s_a[d] - mW, c = s_c[d] - mb;
        s_a[d] = a; s_c[d] = c;
        A += a*a; Bv += a*c; Cv += c*c;
      }
      ws[8]  = A  * (1.0f/DD);
      ws[9]  = Bv * (1.0f/DD);
      ws[10] = Cv * (1.0f/DD);
    }
    __syncthreads();
    if (t < 384) {
      const int m = t >> 7, r = t & 127, e = r >> 5, j = r & 31;
      const float* Wm = (m == 0) ? Wq : (m == 1) ? Wk : Wv;
      float pp = 0.f, qq = 0.f, rr = 0.f;
      for (int d = 0; d < DD; ++d) {
        float w  = Wm[e*DD*DD + d*DD + j];
        float gg = g1[e*DD + d];
        pp += s_a[d]*gg*w;
        qq += s_c[d]*gg*w;
        rr += bb1[e*DD + d]*w;
      }
      float* pqr = ws + WS_WT + 10240;   // f32 tail of image region
      const int base = (m*EE + e)*96 + j;
      pqr[base]      = pp;
      pqr[base + 32] = qq;
      pqr[base + 64] = rr;
    }
  }
}

// ---------------------------------------------------------------------------
// post_attn<NP>: Wo+residual, LN2, FFN1, FFN2+residual, store — for NP
// positions sharing expert e (weight rows read ONCE, used NP times).
// Group-outer DPP keeps per-accumulator summation order identical to R12.
// ---------------------------------------------------------------------------
template<int NP>
__device__ __forceinline__ void post_attn(
    const unsigned* wl, int e, int hh,
    const float* sW, const float* sb,
    const float* g2, const float* bb2,
    const float* b1, const float* b2,
    const float* xv,            // [NP]
    const unsigned (*oq)[4],    // [NP][4]
    float* const* op) {         // [NP]
  float acc[NP][DH];
  #pragma unroll
  for (int u = 0; u < NP; ++u)
    #pragma unroll
    for (int dd = 0; dd < DH; ++dd) {
      const int d = hh*DH + dd;
      acc[u][dd] = xv[u]*sW[d] + sb[d];
    }

  // ---- Wo + residual ----
#define WO_G(PAT, G) { \
    unsigned ol[NP][4]; \
    _Pragma("unroll") for (int u = 0; u < NP; ++u) { \
      ol[u][0]=qdpp<PAT>(oq[u][0]); ol[u][1]=qdpp<PAT>(oq[u][1]); \
      ol[u][2]=qdpp<PAT>(oq[u][2]); ol[u][3]=qdpp<PAT>(oq[u][3]); } \
    _Pragma("unroll") for (int dd = 0; dd < DH; ++dd) { \
      const uint4 w4 = *(const uint4*)&wl[(e*32 + dd*4 + hh)*16 + 4*(G)]; \
      _Pragma("unroll") for (int u = 0; u < NP; ++u) { \
        float a = acc[u][dd]; \
        a = fd2(ol[u][0], w4.x, a); a = fd2(ol[u][1], w4.y, a); \
        a = fd2(ol[u][2], w4.z, a); a = fd2(ol[u][3], w4.w, a); \
        acc[u][dd] = a; } } }
  WO_G(0x00, 0) WO_G(0x55, 1) WO_G(0xAA, 2) WO_G(0xFF, 3)
#undef WO_G

  // ---- LN2 via quad-sum DPP ----
  unsigned zq[NP][4];
  #pragma unroll
  for (int u = 0; u < NP; ++u) {
    float ssum = 0.f;
    #pragma unroll
    for (int dd = 0; dd < DH; ++dd) ssum += acc[u][dd];
    ssum += qdppf<0xB1>(ssum);
    ssum += qdppf<0x4E>(ssum);
    const float m2 = ssum * (1.0f/DD);
    float vs = 0.f;
    #pragma unroll
    for (int dd = 0; dd < DH; ++dd) { float df = acc[u][dd]-m2; vs += df*df; }
    vs += qdppf<0xB1>(vs);
    vs += qdppf<0x4E>(vs);
    const float rs2 = rsqrtf(vs * (1.0f/DD) + 1e-5f);
    #pragma unroll
    for (int j = 0; j < 4; ++j) {
      const int d = hh*DH + 2*j;
      float za = (acc[u][2*j]  -m2)*rs2*g2[e*DD+d]   + bb2[e*DD+d];
      float zb = (acc[u][2*j+1]-m2)*rs2*g2[e*DD+d+1] + bb2[e*DD+d+1];
      zq[u][j] = pkh2(za, zb);
    }
  }

  // ---- FFN1 ----
  float f[NP][16];
  #pragma unroll
  for (int u = 0; u < NP; ++u)
    #pragma unroll
    for (int jj = 0; jj < 16; ++jj) f[u][jj] = b1[e*DFFN + hh*16 + jj];
#define F1_G(PAT, G) { \
    unsigned zl[NP][4]; \
    _Pragma("unroll") for (int u = 0; u < NP; ++u) { \
      zl[u][0]=qdpp<PAT>(zq[u][0]); zl[u][1]=qdpp<PAT>(zq[u][1]); \
      zl[u][2]=qdpp<PAT>(zq[u][2]); zl[u][3]=qdpp<PAT>(zq[u][3]); } \
    _Pragma("unroll") for (int jj = 0; jj < 16; ++jj) { \
      const uint4 w4 = *(const uint4*)&wl[2048 + (e*64 + jj*4 + hh)*16 + 4*(G)]; \
      _Pragma("unroll") for (int u = 0; u < NP; ++u) { \
        float a = f[u][jj]; \
        a = fd2(zl[u][0], w4.x, a); a = fd2(zl[u][1], w4.y, a); \
        a = fd2(zl[u][2], w4.z, a); a = fd2(zl[u][3], w4.w, a); \
        f[u][jj] = a; } } }
  F1_G(0x00, 0) F1_G(0x55, 1) F1_G(0xAA, 2) F1_G(0xFF, 3)
#undef F1_G
  unsigned fq[NP][8];
  #pragma unroll
  for (int u = 0; u < NP; ++u)
    #pragma unroll
    for (int j = 0; j < 8; ++j)
      fq[u][j] = pkh2(fmaxf(f[u][2*j], 0.0f), fmaxf(f[u][2*j+1], 0.0f));

  // ---- FFN2 + residual + b2 ----
  float acc2[NP][DH];
  #pragma unroll
  for (int u = 0; u < NP; ++u)
    #pragma unroll
    for (int dd = 0; dd < DH; ++dd)
      acc2[u][dd] = acc[u][dd] + b2[e*DD + hh*DH + dd];
#define F2_L(PAT, L) { \
    unsigned fl[NP][8]; \
    _Pragma("unroll") for (int u = 0; u < NP; ++u) \
      _Pragma("unroll") for (int j = 0; j < 8; ++j) fl[u][j] = qdpp<PAT>(fq[u][j]); \
    _Pragma("unroll") for (int dd = 0; dd < DH; ++dd) { \
      const int row16 = (e*32 + dd*4 + hh)*16; \
      const uint4 wA = *(const uint4*)&wl[6144 + ((L)>>1)*2048 + row16 + 4*((2*(L))&3)]; \
      const uint4 wB = *(const uint4*)&wl[6144 + ((L)>>1)*2048 + row16 + 4*((2*(L)+1)&3)]; \
      _Pragma("unroll") for (int u = 0; u < NP; ++u) { \
        float a = acc2[u][dd]; \
        a = fd2(fl[u][0], wA.x, a); a = fd2(fl[u][1], wA.y, a); \
        a = fd2(fl[u][2], wA.z, a); a = fd2(fl[u][3], wA.w, a); \
        a = fd2(fl[u][4], wB.x, a); a = fd2(fl[u][5], wB.y, a); \
        a = fd2(fl[u][6], wB.z, a); a = fd2(fl[u][7], wB.w, a); \
        acc2[u][dd] = a; } } }
  F2_L(0x00, 0) F2_L(0x55, 1) F2_L(0xAA, 2) F2_L(0xFF, 3)
#undef F2_L

  #pragma unroll
  for (int u = 0; u < NP; ++u) {
    *(float4*)(op[u])     = make_float4(acc2[u][0], acc2[u][1], acc2[u][2], acc2[u][3]);
    *(float4*)(op[u] + 4) = make_float4(acc2[u][4], acc2[u][5], acc2[u][6], acc2[u][7]);
  }
}

// ---------------------------------------------------------------------------
// Kernel 2 (R13): 512 thr, each thread owns an adjacent sorted-position PAIR
// (2pr, 2pr+1) — every k/v and weight-row LDS read serves 2 positions, so
// per-CU LDS instruction count halves (the measured bottleneck: b128 ~12cyc
// per wave-instr, 16 waves x 306 reads ~= 24us in R12). PQR moved to global
// (off the LDS pipe). Unified masked attention loop over [beg0,end1) is
// exact for uniform AND boundary pairs (end0==beg1 always). One barrier.
// ---------------------------------------------------------------------------
__launch_bounds__(512, 2)
__global__ void fused_kernel(const float* __restrict__ ws,
    const float* __restrict__ g1, const float* __restrict__ bb1,
    const float* __restrict__ sW, const float* __restrict__ sb,
    const float* __restrict__ g2, const float* __restrict__ bb2,
    const float* __restrict__ b1, const float* __restrict__ b2,
    float* __restrict__ out) {
  const int blk = blockIdx.x;
  const int n = blk & 15;
  const int b = blk >> 4;
  const int t = threadIdx.x;      // 0..511
  const int pr = t >> 2;          // pair 0..127
  const int hh = t & 3;
  const int p0 = pr*2, p1 = pr*2 + 1;
  __shared__ unsigned lds[18432];   // [0,8192) kv | [8192,18432) weight image 40KB
  unsigned* wl = lds + 8192;

  // async-stage weight image (10240 uints = 40 x 1KB chunks, 5/wave x 8 waves)
  {
    const unsigned* img = (const unsigned*)ws + WS_WT;
    const int wv = t >> 6;        // 0..7
    const int ln = t & 63;
    #pragma unroll
    for (int i = 0; i < 5; ++i) {
      const int ch = wv*5 + i;
      __builtin_amdgcn_global_load_lds(
          (const __attribute__((address_space(1))) unsigned*)(img + ch*256 + ln*4),
          (__attribute__((address_space(3))) unsigned*)(wl + ch*256 + ln*4),
          16, 0, 0);
    }
  }

  const int* SP  = (const int*)ws + WS_SPI;
  const int* OFF = SP + BB*SS;
  const int o1 = OFF[b*4+1], o2v = OFF[b*4+2], o3 = OFF[b*4+3];
  const int e0 = (p0 >= o1) + (p0 >= o2v) + (p0 >= o3);
  const int e1 = (p1 >= o1) + (p1 >= o2v) + (p1 >= o3);
  const int beg0 = (e0==0) ? 0  : ((e0==1) ? o1 : ((e0==2) ? o2v : o3));
  const int end0 = (e0==0) ? o1 : ((e0==1) ? o2v : ((e0==2) ? o3 : SS));
  const int beg1 = (e1==0) ? 0  : ((e1==1) ? o1 : ((e1==2) ? o2v : o3));
  const int end1 = (e1==0) ? o1 : ((e1==1) ? o2v : ((e1==2) ? o3 : SS));
  const int s_0 = SP[b*SS + p0];
  const int s_1 = SP[b*SS + p1];
  const float xv0 = ws[WS_XNS + (b*SS + s_0)*NCH + n];
  const float xv1 = ws[WS_XNS + (b*SS + s_1)*NCH + n];

  // LN1 collapse (var quadratic in xv)
  const float Ac = ws[8], Bc = ws[9], Cc = ws[10];
  const float rs0 = rsqrtf(fmaf(xv0, fmaf(Ac, xv0, Bc + Bc), Cc) + 1e-5f);
  const float rs1 = rsqrtf(fmaf(xv1, fmaf(Ac, xv1, Bc + Bc), Cc) + 1e-5f);
  const float al0 = rs0*xv0, be0 = rs0;
  const float al1 = rs1*xv1, be1 = rs1;

  // QKV from global PQR (L2-hot, off the LDS pipe)
  const float* pqr = ws + WS_WT + 10240;
  float q0[DH], ka0[DH], va0[DH], q1[DH], ka1[DH], va1[DH];
  {
    #pragma unroll
    for (int m = 0; m < 3; ++m) {
      {
        const float* bp = &pqr[(m*EE + e0)*96 + hh*DH];
        const float4 P0 = *(const float4*)(bp),    P1 = *(const float4*)(bp + 4);
        const float4 Q0 = *(const float4*)(bp+32), Q1 = *(const float4*)(bp + 36);
        const float4 R0 = *(const float4*)(bp+64), R1 = *(const float4*)(bp + 68);
        float* dst = (m == 0) ? q0 : (m == 1) ? ka0 : va0;
        dst[0] = fmaf(al0, P0.x, fmaf(be0, Q0.x, R0.x));
        dst[1] = fmaf(al0, P0.y, fmaf(be0, Q0.y, R0.y));
        dst[2] = fmaf(al0, P0.z, fmaf(be0, Q0.z, R0.z));
        dst[3] = fmaf(al0, P0.w, fmaf(be0, Q0.w, R0.w));
        dst[4] = fmaf(al0, P1.x, fmaf(be0, Q1.x, R1.x));
        dst[5] = fmaf(al0, P1.y, fmaf(be0, Q1.y, R1.y));
        dst[6] = fmaf(al0, P1.z, fmaf(be0, Q1.z, R1.z));
        dst[7] = fmaf(al0, P1.w, fmaf(be0, Q1.w, R1.w));
      }
      {
        const float* bp = &pqr[(m*EE + e1)*96 + hh*DH];
        const float4 P0 = *(const float4*)(bp),    P1 = *(const float4*)(bp + 4);
        const float4 Q0 = *(const float4*)(bp+32), Q1 = *(const float4*)(bp + 36);
        const float4 R0 = *(const float4*)(bp+64), R1 = *(const float4*)(bp + 68);
        float* dst = (m == 0) ? q1 : (m == 1) ? ka1 : va1;
        dst[0] = fmaf(al1, P0.x, fmaf(be1, Q0.x, R0.x));
        dst[1] = fmaf(al1, P0.y, fmaf(be1, Q0.y, R0.y));
        dst[2] = fmaf(al1, P0.z, fmaf(be1, Q0.z, R0.z));
        dst[3] = fmaf(al1, P0.w, fmaf(be1, Q0.w, R0.w));
        dst[4] = fmaf(al1, P1.x, fmaf(be1, Q1.x, R1.x));
        dst[5] = fmaf(al1, P1.y, fmaf(be1, Q1.y, R1.y));
        dst[6] = fmaf(al1, P1.z, fmaf(be1, Q1.z, R1.z));
        dst[7] = fmaf(al1, P1.w, fmaf(be1, Q1.w, R1.w));
      }
    }
  }
  #pragma unroll
  for (int d = 0; d < DH; ++d) { q0[d] *= PRE; q1[d] *= PRE; }

  // write k/v to LDS (f16 packed) — before the single barrier
  *(uint4*)&lds[p0*32 + hh*8]     = make_uint4(pkh2(ka0[0],ka0[1]), pkh2(ka0[2],ka0[3]),
                                               pkh2(ka0[4],ka0[5]), pkh2(ka0[6],ka0[7]));
  *(uint4*)&lds[p0*32 + hh*8 + 4] = make_uint4(pkh2(va0[0],va0[1]), pkh2(va0[2],va0[3]),
                                               pkh2(va0[4],va0[5]), pkh2(va0[6],va0[7]));
  *(uint4*)&lds[p1*32 + hh*8]     = make_uint4(pkh2(ka1[0],ka1[1]), pkh2(ka1[2],ka1[3]),
                                               pkh2(ka1[4],ka1[5]), pkh2(ka1[6],ka1[7]));
  *(uint4*)&lds[p1*32 + hh*8 + 4] = make_uint4(pkh2(va1[0],va1[1]), pkh2(va1[2],va1[3]),
                                               pkh2(va1[4],va1[5]), pkh2(va1[6],va1[7]));
  unsigned qp0[4], qp1[4];
  #pragma unroll
  for (int i = 0; i < 4; ++i) {
    qp0[i] = pkh2(q0[2*i], q0[2*i+1]);
    qp1[i] = pkh2(q1[2*i], q1[2*i+1]);
  }
  float s0_0 = 0.f, s0_1 = 0.f;
  {
    const float4 Ka = *(const float4*)&ws[WS_K0 + e0*DD + hh*DH];
    const float4 Kb = *(const float4*)&ws[WS_K0 + e0*DD + hh*DH + 4];
    s0_0 = q0[0]*Ka.x + q0[1]*Ka.y + q0[2]*Ka.z + q0[3]*Ka.w
         + q0[4]*Kb.x + q0[5]*Kb.y + q0[6]*Kb.z + q0[7]*Kb.w;
    const float4 Kc = *(const float4*)&ws[WS_K0 + e1*DD + hh*DH];
    const float4 Kd = *(const float4*)&ws[WS_K0 + e1*DD + hh*DH + 4];
    s0_1 = q1[0]*Kc.x + q1[1]*Kc.y + q1[2]*Kc.z + q1[3]*Kc.w
         + q1[4]*Kd.x + q1[5]*Kd.y + q1[6]*Kd.z + q1[7]*Kd.w;
  }
  __syncthreads();   // single barrier: staging + kv drained

  // ---- attention: unified masked loop over [beg0, end1) (end0==beg1) ----
  float ws0 = 0.f, ws1 = 0.f;
  __half2 oa0[4], oa1[4];
  #pragma unroll
  for (int i = 0; i < 4; ++i) { oa0[i] = u2h2(0u); oa1[i] = u2h2(0u); }
  int jk = beg0;
  for (; jk + 1 < end1; jk += 2) {
    const uint4 kua = *(const uint4*)&lds[jk*32 + hh*8];
    const uint4 vua = *(const uint4*)&lds[jk*32 + hh*8 + 4];
    const uint4 kub = *(const uint4*)&lds[(jk+1)*32 + hh*8];
    const uint4 vub = *(const uint4*)&lds[(jk+1)*32 + hh*8 + 4];
    float a0a = 0.f, a1a = 0.f, a0b = 0.f, a1b = 0.f;
    a0a = fd2(qp0[0], kua.x, a0a); a0a = fd2(qp0[1], kua.y, a0a);
    a0a = fd2(qp0[2], kua.z, a0a); a0a = fd2(qp0[3], kua.w, a0a);
    a1a = fd2(qp1[0], kua.x, a1a); a1a = fd2(qp1[1], kua.y, a1a);
    a1a = fd2(qp1[2], kua.z, a1a); a1a = fd2(qp1[3], kua.w, a1a);
    a0b = fd2(qp0[0], kub.x, a0b); a0b = fd2(qp0[1], kub.y, a0b);
    a0b = fd2(qp0[2], kub.z, a0b); a0b = fd2(qp0[3], kub.w, a0b);
    a1b = fd2(qp1[0], kub.x, a1b); a1b = fd2(qp1[1], kub.y, a1b);
    a1b = fd2(qp1[2], kub.z, a1b); a1b = fd2(qp1[3], kub.w, a1b);
    const float w0a = (jk   < end0) ? __builtin_amdgcn_exp2f(a0a) : 0.f;
    const float w1a = (jk   >= beg1) ? __builtin_amdgcn_exp2f(a1a) : 0.f;
    const float w0b = (jk+1 < end0) ? __builtin_amdgcn_exp2f(a0b) : 0.f;
    const float w1b = (jk+1 >= beg1) ? __builtin_amdgcn_exp2f(a1b) : 0.f;
    ws0 += w0a + w0b;
    ws1 += w1a + w1b;
    const __half2 h0a = u2h2(pkh2(w0a, w0a));
    const __half2 h1a = u2h2(pkh2(w1a, w1a));
    const __half2 h0b = u2h2(pkh2(w0b, w0b));
    const __half2 h1b = u2h2(pkh2(w1b, w1b));
    oa0[0] = __hfma2(h0a, u2h2(vua.x), oa0[0]);
    oa0[1] = __hfma2(h0a, u2h2(vua.y), oa0[1]);
    oa0[2] = __hfma2(h0a, u2h2(vua.z), oa0[2]);
    oa0[3] = __hfma2(h0a, u2h2(vua.w), oa0[3]);
    oa1[0] = __hfma2(h1a, u2h2(vua.x), oa1[0]);
    oa1[1] = __hfma2(h1a, u2h2(vua.y), oa1[1]);
    oa1[2] = __hfma2(h1a, u2h2(vua.z), oa1[2]);
    oa1[3] = __hfma2(h1a, u2h2(vua.w), oa1[3]);
    oa0[0] = __hfma2(h0b, u2h2(vub.x), oa0[0]);
    oa0[1] = __hfma2(h0b, u2h2(vub.y), oa0[1]);
    oa0[2] = __hfma2(h0b, u2h2(vub.z), oa0[2]);
    oa0[3] = __hfma2(h0b, u2h2(vub.w), oa0[3]);
    oa1[0] = __hfma2(h1b, u2h2(vub.x), oa1[0]);
    oa1[1] = __hfma2(h1b, u2h2(vub.y), oa1[1]);
    oa1[2] = __hfma2(h1b, u2h2(vub.z), oa1[2]);
    oa1[3] = __hfma2(h1b, u2h2(vub.w), oa1[3]);
  }
  if (jk < end1) {
    const uint4 ku = *(const uint4*)&lds[jk*32 + hh*8];
    const uint4 vu = *(const uint4*)&lds[jk*32 + hh*8 + 4];
    float a0 = 0.f, a1 = 0.f;
    a0 = fd2(qp0[0], ku.x, a0); a0 = fd2(qp0[1], ku.y, a0);
    a0 = fd2(qp0[2], ku.z, a0); a0 = fd2(qp0[3], ku.w, a0);
    a1 = fd2(qp1[0], ku.x, a1); a1 = fd2(qp1[1], ku.y, a1);
    a1 = fd2(qp1[2], ku.z, a1); a1 = fd2(qp1[3], ku.w, a1);
    const float w0 = (jk < end0)  ? __builtin_amdgcn_exp2f(a0) : 0.f;
    const float w1 = (jk >= beg1) ? __builtin_amdgcn_exp2f(a1) : 0.f;
    ws0 += w0; ws1 += w1;
    const __half2 h0 = u2h2(pkh2(w0, w0));
    const __half2 h1 = u2h2(pkh2(w1, w1));
    oa0[0] = __hfma2(h0, u2h2(vu.x), oa0[0]);
    oa0[1] = __hfma2(h0, u2h2(vu.y), oa0[1]);
    oa0[2] = __hfma2(h0, u2h2(vu.z), oa0[2]);
    oa0[3] = __hfma2(h0, u2h2(vu.w), oa0[3]);
    oa1[0] = __hfma2(h1, u2h2(vu.x), oa1[0]);
    oa1[1] = __hfma2(h1, u2h2(vu.y), oa1[1]);
    oa1[2] = __hfma2(h1, u2h2(vu.z), oa1[2]);
    oa1[3] = __hfma2(h1, u2h2(vu.w), oa1[3]);
  }

  // finalize o per position (miss-constant + normalize), pack oq
  unsigned oq0[4], oq1[4];
  {
    float o[DH];
    #pragma unroll
    for (int i = 0; i < 4; ++i) { o[2*i] = __low2float(oa0[i]); o[2*i+1] = __high2float(oa0[i]); }
    const int nmis = SS - (end0 - beg0);
    const float w0c = (float)nmis * __builtin_amdgcn_exp2f(s0_0);
    float wsum = ws0 + w0c;
    const float4 Va = *(const float4*)&ws[WS_V0 + e0*DD + hh*DH];
    const float4 Vb = *(const float4*)&ws[WS_V0 + e0*DD + hh*DH + 4];
    o[0] += w0c*Va.x; o[1] += w0c*Va.y; o[2] += w0c*Va.z; o[3] += w0c*Va.w;
    o[4] += w0c*Vb.x; o[5] += w0c*Vb.y; o[6] += w0c*Vb.z; o[7] += w0c*Vb.w;
    const float inv = 1.0f / wsum;
    #pragma unroll
    for (int d = 0; d < DH; ++d) o[d] *= inv;
    #pragma unroll
    for (int j = 0; j < 4; ++j) oq0[j] = pkh2(o[2*j], o[2*j+1]);
  }
  {
    float o[DH];
    #pragma unroll
    for (int i = 0; i < 4; ++i) { o[2*i] = __low2float(oa1[i]); o[2*i+1] = __high2float(oa1[i]); }
    const int nmis = SS - (end1 - beg1);
    const float w0c = (float)nmis * __builtin_amdgcn_exp2f(s0_1);
    float wsum = ws1 + w0c;
    const float4 Va = *(const float4*)&ws[WS_V0 + e1*DD + hh*DH];
    const float4 Vb = *(const float4*)&ws[WS_V0 + e1*DD + hh*DH + 4];
    o[0] += w0c*Va.x; o[1] += w0c*Va.y; o[2] += w0c*Va.z; o[3] += w0c*Va.w;
    o[4] += w0c*Vb.x; o[5] += w0c*Vb.y; o[6] += w0c*Vb.z; o[7] += w0c*Vb.w;
    const float inv = 1.0f / wsum;
    #pragma unroll
    for (int d = 0; d < DH; ++d) o[d] *= inv;
    #pragma unroll
    for (int j = 0; j < 4; ++j) oq1[j] = pkh2(o[2*j], o[2*j+1]);
  }

  float* op0 = out + ((size_t)((b*SS + s_0)*NCH + n))*DD + hh*DH;
  float* op1 = out + ((size_t)((b*SS + s_1)*NCH + n))*DD + hh*DH;

  if (e0 == e1) {
    const float xvv[2] = {xv0, xv1};
    unsigned oqq[2][4];
    #pragma unroll
    for (int j = 0; j < 4; ++j) { oqq[0][j] = oq0[j]; oqq[1][j] = oq1[j]; }
    float* opp[2] = {op0, op1};
    post_attn<2>(wl, e0, hh, sW, sb, g2, bb2, b1, b2, xvv, oqq, opp);
  } else {
    {
      const float xvv[1] = {xv0};
      unsigned oqq[1][4];
      #pragma unroll
      for (int j = 0; j < 4; ++j) oqq[0][j] = oq0[j];
      float* opp[1] = {op0};
      post_attn<1>(wl, e0, hh, sW, sb, g2, bb2, b1, b2, xvv, oqq, opp);
    }
    {
      const float xvv[1] = {xv1};
      unsigned oqq[1][4];
      #pragma unroll
      for (int j = 0; j < 4; ++j) oqq[0][j] = oq1[j];
      float* opp[1] = {op1};
      post_attn<1>(wl, e1, hh, sW, sb, g2, bb2, b1, b2, xvv, oqq, opp);
    }
  }
}

// ---------------------------------------------------------------------------
extern "C" void kernel_launch(void* const* d_in, const int* in_sizes, int n_in,
                              void* d_out, int out_size, void* d_ws, size_t ws_size,
                              hipStream_t stream) {
  (void)in_sizes; (void)n_in; (void)out_size; (void)ws_size;
  const float* x   = (const float*)d_in[0];
  const float* ox  = (const float*)d_in[1];
  const float* sW  = (const float*)d_in[2];
  const float* sb  = (const float*)d_in[3];
  const float* Wq  = (const float*)d_in[4];
  const float* Wk  = (const float*)d_in[5];
  const float* Wv  = (const float*)d_in[6];
  const float* Wo  = (const float*)d_in[7];
  const float* g1  = (const float*)d_in[8];
  const float* b1n = (const float*)d_in[9];
  const float* g2  = (const float*)d_in[10];
  const float* b2n = (const float*)d_in[11];
  const float* W1  = (const float*)d_in[12];
  const float* bf1 = (const float*)d_in[13];
  const float* W2  = (const float*)d_in[14];
  const float* bf2 = (const float*)d_in[15];
  float* out = (float*)d_out;
  float* ws  = (float*)d_ws;

  decomp_prep_kernel<<<276, 1024, 0, stream>>>(x, ox, sW, sb, g1, b1n,
                                               Wq, Wk, Wv, Wo, W1, W2, ws);
  fused_kernel<<<BB*NCH, 512, 0, stream>>>(ws, g1, b1n, sW, sb, g2, b2n,
                                           bf1, bf2, out);
}

// Round 4
// 138.436 us; speedup vs baseline: 1.1033x; 1.1033x over previous
//
#include <hip/hip_runtime.h>
#include <hip/hip_fp16.h>
#include <math.h>

#define BB 16
#define SS 256
#define CC 17
#define NCH 16
#define DD 32
#define DFFN 64
#define HH 4
#define DH 8
#define EE 4

// ws layout (4-byte units):
//  [8..10]     A,B,C LN1-collapse scalars
//  [16 ..143]  K0[e][d]   [144..271] V0[e][d]
//  [512..66047]  XNS[b][s][n]
//  ints at WS_SPI: SP[b][p] (4096), OFF[b][e] (64)
//  WS_WT: weight image (12288 uints):
//    [0,2048) WoT | [2048,6144) W1T | [6144,10240) W2T 2 planes
//    [10240,11392) PQR f32 (3 mats x 4 e x {P[32],Q[32],R[32]}) | pad to 12288
#define WS_K0 16
#define WS_V0 144
#define WS_XNS 512
#define WS_SPI (WS_XNS + BB*SS*NCH)          // 66048
#define WS_WT  (WS_SPI + BB*SS + 64)         // 70208

#define PRE 0.51006977f   // (1/sqrt(8)) * log2(e)

typedef __fp16 hv2 __attribute__((ext_vector_type(2)));

__device__ __forceinline__ unsigned pkh2(float a, float b) {
  hv2 r = __builtin_amdgcn_cvt_pkrtz(a, b);
  unsigned u; __builtin_memcpy(&u, &r, 4);
  return u;
}
__device__ __forceinline__ float fd2(unsigned a, unsigned b, float c) {
  hv2 av, bv;
  __builtin_memcpy(&av, &a, 4);
  __builtin_memcpy(&bv, &b, 4);
  return __builtin_amdgcn_fdot2(av, bv, c, false);
}
__device__ __forceinline__ __half2 u2h2(unsigned u) {
  __half2 h; __builtin_memcpy(&h, &u, 4); return h;
}
__device__ __forceinline__ __half2 shx_h2(__half2 x, int m) {
  int v; __builtin_memcpy(&v, &x, 4);
  v = __shfl_xor(v, m);
  __half2 r; __builtin_memcpy(&r, &v, 4);
  return r;
}
template<int PAT>
__device__ __forceinline__ unsigned qdpp(unsigned v) {
  return (unsigned)__builtin_amdgcn_mov_dpp((int)v, PAT, 0xF, 0xF, true);
}
template<int PAT>
__device__ __forceinline__ float qdppf(float v) {
  return __uint_as_float(qdpp<PAT>(__float_as_uint(v)));
}

// ---------------------------------------------------------------------------
// Kernel 1 (1024 thr): decomp (blocks 0..255), prep (256..271),
// weight-image convert (272..274), LN1-collapse PQR/ABC (275).  [= R12]
// ---------------------------------------------------------------------------
__launch_bounds__(1024)
__global__ void decomp_prep_kernel(const float* __restrict__ x,
                                   const float* __restrict__ ox,
                                   const float* __restrict__ sW,
                                   const float* __restrict__ sb,
                                   const float* __restrict__ g1,
                                   const float* __restrict__ bb1,
                                   const float* __restrict__ Wq,
                                   const float* __restrict__ Wk,
                                   const float* __restrict__ Wv,
                                   const float* __restrict__ Wo,
                                   const float* __restrict__ W1,
                                   const float* __restrict__ W2,
                                   float* __restrict__ ws) {
  const int t = threadIdx.x;  // 1024
  if (blockIdx.x < 256) {
    const int b = blockIdx.x / NCH;
    const int c = blockIdx.x % NCH;
    __shared__ float xs[SS];
    __shared__ float prr[1024], pii[1024];
    __shared__ float amp[129];
    __shared__ float2 YY[129];
    __shared__ float sth;
    if (t < SS) xs[t] = x[(b*SS + t)*CC + c];
    __syncthreads();
    const float TH0 = 0.024543692606170259f;  // 2*pi/256
    {
      const int f = (t & 127) + 1;
      const int chunk = t >> 7;
      const int s0 = chunk * 32;
      const int ph0 = (f * s0) & 255;
      float si, cr; sincosf(TH0*(float)ph0, &si, &cr);
      float s1, c1; sincosf(TH0*(float)f, &s1, &c1);
      float xr = 0.f, xi = 0.f;
      #pragma unroll 4
      for (int k = 0; k < 32; ++k) {
        float xvv = xs[s0 + k];
        xr += xvv * cr;
        xi -= xvv * si;
        float nc = cr*c1 - si*s1;
        si = si*c1 + cr*s1;
        cr = nc;
      }
      prr[t] = xr; pii[t] = xi;
    }
    __syncthreads();
    if (t < 128) {
      float xr = 0.f, xi = 0.f;
      #pragma unroll
      for (int k2 = 0; k2 < 8; ++k2) { xr += prr[t + 128*k2]; xi += pii[t + 128*k2]; }
      prr[t] = xr; pii[t] = xi;
      amp[t+1] = sqrtf(xr*xr + xi*xi);
    }
    __syncthreads();
    if (t < 64) {   // wave 0: top-4 knockout
      float a0 = amp[t+1], a1 = amp[t+65];
      int i0 = t+1, i1 = t+65;
      float th = -1e30f;
      for (int r = 0; r < 4; ++r) {
        float mv = (a0 > a1) ? a0 : a1;
        int   mi = (a0 > a1) ? i0 : i1;
        for (int off = 32; off > 0; off >>= 1) {
          float ov = __shfl_xor(mv, off);
          int   oi = __shfl_xor(mi, off);
          if (ov > mv || (ov == mv && oi < mi)) { mv = ov; mi = oi; }
        }
        th = mv;
        if (mi == i0) a0 = -1e30f;
        if (mi == i1) a1 = -1e30f;
      }
      if (t == 0) sth = th;
    }
    __syncthreads();
    if (t < 128) {
      const int f = t + 1;
      float wgt = (amp[f] >= sth) ? ((f == 128) ? 1.0f : 2.0f) * (1.0f/256.0f) : 0.0f;
      YY[f] = make_float2(wgt * prr[t], wgt * pii[t]);
    }
    __syncthreads();
    {
      const int s = t & 255;
      const int fc = t >> 8;
      const int f0 = 1 + fc*32;
      const int ph0 = (s * f0) & 255;
      float si, cr; sincosf(TH0*(float)ph0, &si, &cr);
      float s1, c1; sincosf(TH0*(float)s, &s1, &c1);
      float acc = 0.f;
      #pragma unroll 4
      for (int k = 0; k < 32; ++k) {
        float2 y = YY[f0 + k];
        acc += y.x*cr - y.y*si;
        float nc = cr*c1 - si*s1;
        si = si*c1 + cr*s1;
        cr = nc;
      }
      prr[t] = acc;
    }
    __syncthreads();
    if (t < 256) {
      float season = prr[t] + prr[t+256] + prr[t+512] + prr[t+768];
      float s4 = 0.f, s8 = 0.f, s12 = 0.f;
      #pragma unroll
      for (int j = 0; j < 4; ++j)  { int p = t + j - 1; p = p < 0 ? 0 : (p > SS-1 ? SS-1 : p); s4  += xs[p]; }
      #pragma unroll
      for (int j = 0; j < 8; ++j)  { int p = t + j - 3; p = p < 0 ? 0 : (p > SS-1 ? SS-1 : p); s8  += xs[p]; }
      #pragma unroll
      for (int j = 0; j < 12; ++j) { int p = t + j - 5; p = p < 0 ? 0 : (p > SS-1 ? SS-1 : p); s12 += xs[p]; }
      float trend = (s4 * 0.25f + s8 * 0.125f + s12 * (1.0f/12.0f)) * (1.0f/3.0f);
      ws[WS_XNS + (b*SS + t)*NCH + c] = xs[t] + season + trend;
    }
  } else if (blockIdx.x < 272) {
    const int b = blockIdx.x - 256;
    __shared__ float red[32];
    __shared__ int asg[SS];
    __shared__ int cnt[EE];
    __shared__ float z0[EE*DD];
    float mn = 3e38f, mx = -3e38f;
    #pragma unroll
    for (int k = 0; k < 4; ++k) {
      float v = ox[(t + k*1024)*2 + 1];
      mn = fminf(mn, v); mx = fmaxf(mx, v);
    }
    for (int off = 32; off > 0; off >>= 1) {
      mn = fminf(mn, __shfl_xor(mn, off));
      mx = fmaxf(mx, __shfl_xor(mx, off));
    }
    if ((t & 63) == 0) { red[(t>>6)*2] = mn; red[(t>>6)*2+1] = mx; }
    __syncthreads();
    mn = red[0]; mx = red[1];
    #pragma unroll
    for (int w = 1; w < 16; ++w) { mn = fminf(mn, red[w*2]); mx = fmaxf(mx, red[w*2+1]); }
    const float step = (mx - mn) * 0.25f;
    const float e1 = mn + step, e2 = mn + 2.f*step, e3 = mn + 3.f*step;
    if (t < 256) {
      float sc = ox[(b*SS + t)*2 + 1];
      asg[t] = (sc >= e1) + (sc >= e2) + (sc >= e3);
    }
    __syncthreads();
    if (t < EE) {
      int c = 0;
      for (int s2 = 0; s2 < SS; ++s2) c += (asg[s2] == t);
      cnt[t] = c;
    }
    __syncthreads();
    int* SPw  = (int*)ws + WS_SPI;
    int* OFFw = SPw + BB*SS;
    if (t < EE) {
      int off = 0;
      for (int i = 0; i < t; ++i) off += cnt[i];
      OFFw[b*EE + t] = off;
      int kp = off;
      for (int s2 = 0; s2 < SS; ++s2) if (asg[s2] == t) SPw[b*SS + (kp++)] = s2;
    }
    if (t < 128) {
      int ee = t >> 5, d = t & 31;
      float m = 0.f;
      for (int i = 0; i < DD; ++i) m += sb[i];
      m *= (1.0f/DD);
      float var = 0.f;
      for (int i = 0; i < DD; ++i) { float df = sb[i]-m; var += df*df; }
      var *= (1.0f/DD);
      float rs = rsqrtf(var + 1e-5f);
      z0[ee*DD + d] = (sb[d]-m)*rs*g1[ee*DD+d] + bb1[ee*DD+d];
    }
    __syncthreads();
    if (b == 0 && t < 128) {
      int ee = t >> 5, d = t & 31;
      float k0 = 0.f, v0 = 0.f;
      for (int i = 0; i < DD; ++i) {
        float zz = z0[ee*DD + i];
        k0 += zz * Wk[ee*DD*DD + i*DD + d];
        v0 += zz * Wv[ee*DD*DD + i*DD + d];
      }
      ws[WS_K0 + ee*DD + d] = k0;
      ws[WS_V0 + ee*DD + d] = v0;
    }
  } else if (blockIdx.x < 275) {
    // weight-image converters: 3 blocks x 4096 slots cover [0, 10240)
    unsigned* img = (unsigned*)ws + WS_WT;
    const int base_u = (blockIdx.x - 272)*4096;
    #pragma unroll
    for (int i = 0; i < 4; ++i) {
      int u = base_u + i*1024 + t;
      if (u < 10240) {
        unsigned val;
        if (u < 2048) {                  // WoT
          int row = u >> 4, ip = u & 15;
          int e = row >> 5, qq = row & 31;
          int d = (qq & 3)*8 + (qq >> 2);
          const float* src = Wo + e*1024 + d;
          val = pkh2(src[ip*64], src[ip*64 + 32]);
        } else if (u < 6144) {           // W1T
          int r = u - 2048;
          int row = r >> 4, ip = r & 15;
          int e = row >> 6, qq = row & 63;
          int j = (qq & 3)*16 + (qq >> 2);
          const float* src = W1 + e*2048 + j;
          val = pkh2(src[ip*128], src[ip*128 + 64]);
        } else {                         // W2T (two planes)
          int r = u - 6144;
          int a = r >> 11, rr = r & 2047;
          int row = rr >> 4, ip = rr & 15;
          int e = row >> 5, qq = row & 31;
          int d = (qq & 3)*8 + (qq >> 2);
          int jp = a*16 + ip;
          const float* src = W2 + e*2048 + d;
          val = pkh2(src[2*jp*32], src[(2*jp+1)*32]);
        }
        img[u] = val;
      }
    }
  } else {
    // block 275: LN1-collapse precompute.
    __shared__ float s_a[DD], s_c[DD];
    if (t < DD) { s_a[t] = sW[t]; s_c[t] = sb[t]; }
    __syncthreads();
    if (t == 0) {
      float mW = 0.f, mb = 0.f;
      for (int d = 0; d < DD; ++d) { mW += s_a[d]; mb += s_c[d]; }
      mW *= (1.0f/DD); mb *= (1.0f/DD);
      float A = 0.f, Bv = 0.f, Cv = 0.f;
      for (int d = 0; d < DD; ++d) {
        float a = s_a[d] - mW, c = s_c[d] - mb;
        s_a[d] = a; s_c[d] = c;
        A += a*a; Bv += a*c; Cv += c*c;
      }
      ws[8]  = A  * (1.0f/DD);
      ws[9]  = Bv * (1.0f/DD);
      ws[10] = Cv * (1.0f/DD);
    }
    __syncthreads();
    if (t < 384) {
      const int m = t >> 7, r = t & 127, e = r >> 5, j = r & 31;
      const float* Wm = (m == 0) ? Wq : (m == 1) ? Wk : Wv;
      float pp = 0.f, qq = 0.f, rr = 0.f;
      for (int d = 0; d < DD; ++d) {
        float w  = Wm[e*DD*DD + d*DD + j];
        float gg = g1[e*DD + d];
        pp += s_a[d]*gg*w;
        qq += s_c[d]*gg*w;
        rr += bb1[e*DD + d]*w;
      }
      float* pqr = ws + WS_WT + 10240;   // f32 tail of image region
      const int base = (m*EE + e)*96 + j;
      pqr[base]      = pp;
      pqr[base + 32] = qq;
      pqr[base + 64] = rr;
    }
  }
}

// ---------------------------------------------------------------------------
// Kernel 2 (R14): 1024 thr (16 waves/CU — R13 showed 8 waves is latency-
// bound), within-wave SPLIT-2 attention. Lane layout t = pr*8 + sk*4 + hh:
// quad = 4 heads of ONE position (DPP machinery unchanged, p = 2*pr + sk);
// the two quads of an 8-lane group are the adjacent sorted pair. Each lane
// sweeps keys jk == lo+sk (mod 2) of the pair's union range, scoring BOTH
// positions per k/v read (sibling packed q via one shfl_xor(4)), partials
// combined with one shfl_xor(4) butterfly. Attn LDS b128: 128 -> 64/thread,
// per-wave ~306 -> ~242 (the measured bottleneck: broadcast b128 ~12cyc/
// wave-instr, return-bus bound; 2 distinct rows/instr is 2-way bank alias =
// free). QKV/staging/post-attn byte-identical to R12.
// ---------------------------------------------------------------------------
__launch_bounds__(1024, 4)
__global__ void fused_kernel(const float* __restrict__ ws,
    const float* __restrict__ g1, const float* __restrict__ bb1,
    const float* __restrict__ sW, const float* __restrict__ sb,
    const float* __restrict__ g2, const float* __restrict__ bb2,
    const float* __restrict__ b1, const float* __restrict__ b2,
    float* __restrict__ out) {
  const int blk = blockIdx.x;
  const int n = blk & 15;
  const int b = blk >> 4;
  const int t = threadIdx.x;
  const int hh = t & 3;
  const int sk = (t >> 2) & 1;
  const int p  = (t >> 3)*2 + sk;     // own sorted position 0..255
  const int psib = p ^ 1;             // pair sibling
  __shared__ unsigned lds[20480];    // [0,8192) kv | [8192,20480) weight image
  unsigned* wl = lds + 8192;

  // async-stage weight image (12288 uints = 48 x 1KB chunks, 3/wave)
  {
    const unsigned* img = (const unsigned*)ws + WS_WT;
    const int wv = t >> 6;
    const int ln = t & 63;
    #pragma unroll
    for (int i = 0; i < 3; ++i) {
      const int ch = wv*3 + i;
      __builtin_amdgcn_global_load_lds(
          (const __attribute__((address_space(1))) unsigned*)(img + ch*256 + ln*4),
          (__attribute__((address_space(3))) unsigned*)(wl + ch*256 + ln*4),
          16, 0, 0);
    }
  }

  const int* SP  = (const int*)ws + WS_SPI;
  const int* OFF = SP + BB*SS;
  const int o1 = OFF[b*4+1], o2v = OFF[b*4+2], o3 = OFF[b*4+3];
  const int e = (p >= o1) + (p >= o2v) + (p >= o3);
  const int beg = (e==0) ? 0  : ((e==1) ? o1 : ((e==2) ? o2v : o3));
  const int end = (e==0) ? o1 : ((e==1) ? o2v : ((e==2) ? o3 : SS));
  const int es = (psib >= o1) + (psib >= o2v) + (psib >= o3);
  const int begs = (es==0) ? 0  : ((es==1) ? o1 : ((es==2) ? o2v : o3));
  const int ends = (es==0) ? o1 : ((es==1) ? o2v : ((es==2) ? o3 : SS));
  const int s = SP[b*SS + p];
  const float xv = ws[WS_XNS + (b*SS + s)*NCH + n];

  // LN1 collapse: var is a quadratic in xv
  const float Ac = ws[8], Bc = ws[9], Cc = ws[10];
  const float var = fmaf(xv, fmaf(Ac, xv, Bc + Bc), Cc);
  const float rs = rsqrtf(var + 1e-5f);
  const float alpha = rs * xv, beta = rs;
  __syncthreads();   // barrier 1: weight image staged (vmcnt drained)

  // qkv via precomputed PQR (own position): q[dd] holds dim hh*8+dd
  const float* pqr = (const float*)(wl + 10240);
  float q[DH], kk[DH], vv[DH];
  #pragma unroll
  for (int m = 0; m < 3; ++m) {
    const float* bp = &pqr[(m*EE + e)*96 + hh*DH];
    const float4 P0 = *(const float4*)(bp);
    const float4 P1 = *(const float4*)(bp + 4);
    const float4 Q0 = *(const float4*)(bp + 32);
    const float4 Q1 = *(const float4*)(bp + 36);
    const float4 R0 = *(const float4*)(bp + 64);
    const float4 R1 = *(const float4*)(bp + 68);
    float* dst = (m == 0) ? q : (m == 1) ? kk : vv;
    dst[0] = fmaf(alpha, P0.x, fmaf(beta, Q0.x, R0.x));
    dst[1] = fmaf(alpha, P0.y, fmaf(beta, Q0.y, R0.y));
    dst[2] = fmaf(alpha, P0.z, fmaf(beta, Q0.z, R0.z));
    dst[3] = fmaf(alpha, P0.w, fmaf(beta, Q0.w, R0.w));
    dst[4] = fmaf(alpha, P1.x, fmaf(beta, Q1.x, R1.x));
    dst[5] = fmaf(alpha, P1.y, fmaf(beta, Q1.y, R1.y));
    dst[6] = fmaf(alpha, P1.z, fmaf(beta, Q1.z, R1.z));
    dst[7] = fmaf(alpha, P1.w, fmaf(beta, Q1.w, R1.w));
  }
  #pragma unroll
  for (int dd = 0; dd < DH; ++dd) q[dd] *= PRE;

  // write k/v of own position to LDS (f16 packed)
  *(uint4*)&lds[p*32 + hh*8]     = make_uint4(pkh2(kk[0],kk[1]), pkh2(kk[2],kk[3]),
                                              pkh2(kk[4],kk[5]), pkh2(kk[6],kk[7]));
  *(uint4*)&lds[p*32 + hh*8 + 4] = make_uint4(pkh2(vv[0],vv[1]), pkh2(vv[2],vv[3]),
                                              pkh2(vv[4],vv[5]), pkh2(vv[6],vv[7]));
  unsigned qp2[4], qsb[4];
  #pragma unroll
  for (int i = 0; i < 4; ++i) qp2[i] = pkh2(q[2*i], q[2*i+1]);
  #pragma unroll
  for (int i = 0; i < 4; ++i) qsb[i] = (unsigned)__shfl_xor((int)qp2[i], 4);
  float s0 = 0.f;
  #pragma unroll
  for (int d = 0; d < DH; ++d) s0 += q[d] * ws[WS_K0 + e*DD + hh*DH + d];
  __syncthreads();   // barrier 2: kv staged — LAST barrier

  // ---- split-2 attention over the pair's union range ----
  const int lo = (beg < begs) ? beg : begs;
  const int hi = (end > ends) ? end : ends;
  float wsO = 0.f, wsS = 0.f;
  __half2 oaO[4], oaS[4];
  #pragma unroll
  for (int i = 0; i < 4; ++i) { oaO[i] = u2h2(0u); oaS[i] = u2h2(0u); }
  int jk = lo + sk;      // this lane's key slots: lo+sk, lo+sk+2, ...
  for (; jk + 2 < hi; jk += 4) {
    const uint4 ku0 = *(const uint4*)&lds[jk*32 + hh*8];
    const uint4 vu0 = *(const uint4*)&lds[jk*32 + hh*8 + 4];
    const uint4 ku1 = *(const uint4*)&lds[(jk+2)*32 + hh*8];
    const uint4 vu1 = *(const uint4*)&lds[(jk+2)*32 + hh*8 + 4];
    float aO0 = 0.f, aS0 = 0.f, aO1 = 0.f, aS1 = 0.f;
    aO0 = fd2(qp2[0], ku0.x, aO0); aO0 = fd2(qp2[1], ku0.y, aO0);
    aO0 = fd2(qp2[2], ku0.z, aO0); aO0 = fd2(qp2[3], ku0.w, aO0);
    aS0 = fd2(qsb[0], ku0.x, aS0); aS0 = fd2(qsb[1], ku0.y, aS0);
    aS0 = fd2(qsb[2], ku0.z, aS0); aS0 = fd2(qsb[3], ku0.w, aS0);
    aO1 = fd2(qp2[0], ku1.x, aO1); aO1 = fd2(qp2[1], ku1.y, aO1);
    aO1 = fd2(qp2[2], ku1.z, aO1); aO1 = fd2(qp2[3], ku1.w, aO1);
    aS1 = fd2(qsb[0], ku1.x, aS1); aS1 = fd2(qsb[1], ku1.y, aS1);
    aS1 = fd2(qsb[2], ku1.z, aS1); aS1 = fd2(qsb[3], ku1.w, aS1);
    const float wO0 = (jk   >= beg  && jk   < end)  ? __builtin_amdgcn_exp2f(aO0) : 0.f;
    const float wS0 = (jk   >= begs && jk   < ends) ? __builtin_amdgcn_exp2f(aS0) : 0.f;
    const float wO1 = (jk+2 >= beg  && jk+2 < end)  ? __builtin_amdgcn_exp2f(aO1) : 0.f;
    const float wS1 = (jk+2 >= begs && jk+2 < ends) ? __builtin_amdgcn_exp2f(aS1) : 0.f;
    wsO += wO0 + wO1;
    wsS += wS0 + wS1;
    const __half2 hO0 = u2h2(pkh2(wO0, wO0));
    const __half2 hS0 = u2h2(pkh2(wS0, wS0));
    const __half2 hO1 = u2h2(pkh2(wO1, wO1));
    const __half2 hS1 = u2h2(pkh2(wS1, wS1));
    oaO[0] = __hfma2(hO0, u2h2(vu0.x), oaO[0]);
    oaO[1] = __hfma2(hO0, u2h2(vu0.y), oaO[1]);
    oaO[2] = __hfma2(hO0, u2h2(vu0.z), oaO[2]);
    oaO[3] = __hfma2(hO0, u2h2(vu0.w), oaO[3]);
    oaS[0] = __hfma2(hS0, u2h2(vu0.x), oaS[0]);
    oaS[1] = __hfma2(hS0, u2h2(vu0.y), oaS[1]);
    oaS[2] = __hfma2(hS0, u2h2(vu0.z), oaS[2]);
    oaS[3] = __hfma2(hS0, u2h2(vu0.w), oaS[3]);
    oaO[0] = __hfma2(hO1, u2h2(vu1.x), oaO[0]);
    oaO[1] = __hfma2(hO1, u2h2(vu1.y), oaO[1]);
    oaO[2] = __hfma2(hO1, u2h2(vu1.z), oaO[2]);
    oaO[3] = __hfma2(hO1, u2h2(vu1.w), oaO[3]);
    oaS[0] = __hfma2(hS1, u2h2(vu1.x), oaS[0]);
    oaS[1] = __hfma2(hS1, u2h2(vu1.y), oaS[1]);
    oaS[2] = __hfma2(hS1, u2h2(vu1.z), oaS[2]);
    oaS[3] = __hfma2(hS1, u2h2(vu1.w), oaS[3]);
  }
  if (jk < hi) {
    const uint4 ku = *(const uint4*)&lds[jk*32 + hh*8];
    const uint4 vu = *(const uint4*)&lds[jk*32 + hh*8 + 4];
    float aO = 0.f, aS = 0.f;
    aO = fd2(qp2[0], ku.x, aO); aO = fd2(qp2[1], ku.y, aO);
    aO = fd2(qp2[2], ku.z, aO); aO = fd2(qp2[3], ku.w, aO);
    aS = fd2(qsb[0], ku.x, aS); aS = fd2(qsb[1], ku.y, aS);
    aS = fd2(qsb[2], ku.z, aS); aS = fd2(qsb[3], ku.w, aS);
    const float wO = (jk >= beg  && jk < end)  ? __builtin_amdgcn_exp2f(aO) : 0.f;
    const float wS = (jk >= begs && jk < ends) ? __builtin_amdgcn_exp2f(aS) : 0.f;
    wsO += wO; wsS += wS;
    const __half2 hO = u2h2(pkh2(wO, wO));
    const __half2 hS = u2h2(pkh2(wS, wS));
    oaO[0] = __hfma2(hO, u2h2(vu.x), oaO[0]);
    oaO[1] = __hfma2(hO, u2h2(vu.y), oaO[1]);
    oaO[2] = __hfma2(hO, u2h2(vu.z), oaO[2]);
    oaO[3] = __hfma2(hO, u2h2(vu.w), oaO[3]);
    oaS[0] = __hfma2(hS, u2h2(vu.x), oaS[0]);
    oaS[1] = __hfma2(hS, u2h2(vu.y), oaS[1]);
    oaS[2] = __hfma2(hS, u2h2(vu.z), oaS[2]);
    oaS[3] = __hfma2(hS, u2h2(vu.w), oaS[3]);
  }
  // butterfly: partner's sibling-partial IS our own position's other half
  float wsum = wsO + __shfl_xor(wsS, 4);
  __half2 o2[4];
  #pragma unroll
  for (int i = 0; i < 4; ++i) o2[i] = __hadd2(oaO[i], shx_h2(oaS[i], 4));

  // off-expert keys: constant score s0, constant value v0
  float o[DH];
  #pragma unroll
  for (int i = 0; i < 4; ++i) {
    o[2*i]   = __low2float(o2[i]);
    o[2*i+1] = __high2float(o2[i]);
  }
  const int nmis = SS - (end - beg);
  float w0 = (float)nmis * __builtin_amdgcn_exp2f(s0);
  wsum += w0;
  #pragma unroll
  for (int d = 0; d < DH; ++d) o[d] += w0 * ws[WS_V0 + e*DD + hh*DH + d];
  float inv = 1.0f / wsum;
  #pragma unroll
  for (int d = 0; d < DH; ++d) o[d] *= inv;

  // ---- o gather via DPP quad broadcast (no barrier, no LDS) ----
  unsigned oq[4];
  #pragma unroll
  for (int j = 0; j < 4; ++j) oq[j] = pkh2(o[2*j], o[2*j+1]);
  unsigned ovp[16];
  #pragma unroll
  for (int j = 0; j < 4; ++j) {
    ovp[j]    = qdpp<0x00>(oq[j]);
    ovp[4+j]  = qdpp<0x55>(oq[j]);
    ovp[8+j]  = qdpp<0xAA>(oq[j]);
    ovp[12+j] = qdpp<0xFF>(oq[j]);
  }

  // Wo + residual: acc[dd] = h2 at dim hh*8+dd
  float acc[DH];
  #pragma unroll
  for (int dd = 0; dd < DH; ++dd) {
    int d = hh*DH + dd;
    const uint4* row = (const uint4*)&wl[(e*32 + dd*4 + hh)*16];
    float a = xv * sW[d] + sb[d];
    #pragma unroll
    for (int g4 = 0; g4 < 4; ++g4) {
      uint4 w4 = row[g4];
      a = fd2(ovp[4*g4+0], w4.x, a); a = fd2(ovp[4*g4+1], w4.y, a);
      a = fd2(ovp[4*g4+2], w4.z, a); a = fd2(ovp[4*g4+3], w4.w, a);
    }
    acc[dd] = a;
  }

  // ---- LN2 via quad-sum DPP reductions ----
  float ssum = 0.f;
  #pragma unroll
  for (int dd = 0; dd < DH; ++dd) ssum += acc[dd];
  ssum += qdppf<0xB1>(ssum);
  ssum += qdppf<0x4E>(ssum);
  float m2 = ssum * (1.0f/DD);
  float vs = 0.f;
  #pragma unroll
  for (int dd = 0; dd < DH; ++dd) { float df = acc[dd]-m2; vs += df*df; }
  vs += qdppf<0xB1>(vs);
  vs += qdppf<0x4E>(vs);
  float rs2 = rsqrtf(vs * (1.0f/DD) + 1e-5f);
  unsigned zq[4];
  #pragma unroll
  for (int j = 0; j < 4; ++j) {
    int d = hh*DH + 2*j;
    float za = (acc[2*j]  -m2)*rs2*g2[e*DD+d]   + bb2[e*DD+d];
    float zb = (acc[2*j+1]-m2)*rs2*g2[e*DD+d+1] + bb2[e*DD+d+1];
    zq[j] = pkh2(za, zb);
  }
  unsigned zp2[16];
  #pragma unroll
  for (int j = 0; j < 4; ++j) {
    zp2[j]    = qdpp<0x00>(zq[j]);
    zp2[4+j]  = qdpp<0x55>(zq[j]);
    zp2[8+j]  = qdpp<0xAA>(zq[j]);
    zp2[12+j] = qdpp<0xFF>(zq[j]);
  }

  // FFN1: f[hh*16 .. +16)
  float f[16];
  #pragma unroll
  for (int jj = 0; jj < 16; ++jj) {
    const uint4* row = (const uint4*)&wl[2048 + (e*64 + jj*4 + hh)*16];
    float a = b1[e*DFFN + hh*16 + jj];
    #pragma unroll
    for (int g4 = 0; g4 < 4; ++g4) {
      uint4 w4 = row[g4];
      a = fd2(zp2[4*g4+0], w4.x, a); a = fd2(zp2[4*g4+1], w4.y, a);
      a = fd2(zp2[4*g4+2], w4.z, a); a = fd2(zp2[4*g4+3], w4.w, a);
    }
    f[jj] = fmaxf(a, 0.0f);
  }
  // ---- f gather via DPP quad broadcast ----
  unsigned fq[8];
  #pragma unroll
  for (int j = 0; j < 8; ++j) fq[j] = pkh2(f[2*j], f[2*j+1]);
  unsigned fu[32];
  #pragma unroll
  for (int j = 0; j < 8; ++j) {
    fu[j]    = qdpp<0x00>(fq[j]);
    fu[8+j]  = qdpp<0x55>(fq[j]);
    fu[16+j] = qdpp<0xAA>(fq[j]);
    fu[24+j] = qdpp<0xFF>(fq[j]);
  }

  // FFN2 + residual + b2
  float acc2[DH];
  #pragma unroll
  for (int dd = 0; dd < DH; ++dd) {
    int d = hh*DH + dd;
    const int row16 = (e*32 + dd*4 + hh)*16;
    float a = acc[dd] + b2[e*DD + d];
    #pragma unroll
    for (int g4 = 0; g4 < 8; ++g4) {
      const int plane = (g4 >> 2);
      uint4 w4 = *(const uint4*)&wl[6144 + plane*2048 + row16 + 4*(g4 & 3)];
      a = fd2(fu[4*g4+0], w4.x, a); a = fd2(fu[4*g4+1], w4.y, a);
      a = fd2(fu[4*g4+2], w4.z, a); a = fd2(fu[4*g4+3], w4.w, a);
    }
    acc2[dd] = a;
  }
  float* op = out + ((size_t)((b*SS + s)*NCH + n))*DD + hh*DH;
  *(float4*)(op)     = make_float4(acc2[0], acc2[1], acc2[2], acc2[3]);
  *(float4*)(op + 4) = make_float4(acc2[4], acc2[5], acc2[6], acc2[7]);
}

// ---------------------------------------------------------------------------
extern "C" void kernel_launch(void* const* d_in, const int* in_sizes, int n_in,
                              void* d_out, int out_size, void* d_ws, size_t ws_size,
                              hipStream_t stream) {
  (void)in_sizes; (void)n_in; (void)out_size; (void)ws_size;
  const float* x   = (const float*)d_in[0];
  const float* ox  = (const float*)d_in[1];
  const float* sW  = (const float*)d_in[2];
  const float* sb  = (const float*)d_in[3];
  const float* Wq  = (const float*)d_in[4];
  const float* Wk  = (const float*)d_in[5];
  const float* Wv  = (const float*)d_in[6];
  const float* Wo  = (const float*)d_in[7];
  const float* g1  = (const float*)d_in[8];
  const float* b1n = (const float*)d_in[9];
  const float* g2  = (const float*)d_in[10];
  const float* b2n = (const float*)d_in[11];
  const float* W1  = (const float*)d_in[12];
  const float* bf1 = (const float*)d_in[13];
  const float* W2  = (const float*)d_in[14];
  const float* bf2 = (const float*)d_in[15];
  float* out = (float*)d_out;
  float* ws  = (float*)d_ws;

  decomp_prep_kernel<<<276, 1024, 0, stream>>>(x, ox, sW, sb, g1, b1n,
                                               Wq, Wk, Wv, Wo, W1, W2, ws);
  fused_kernel<<<BB*NCH, 1024, 0, stream>>>(ws, g1, b1n, sW, sb, g2, b2n,
                                            bf1, bf2, out);
}

// Round 6
// 135.751 us; speedup vs baseline: 1.1251x; 1.0198x over previous
//
#include <hip/hip_runtime.h>
#include <hip/hip_fp16.h>
#include <math.h>

#define BB 16
#define SS 256
#define CC 17
#define NCH 16
#define DD 32
#define DFFN 64
#define HH 4
#define DH 8
#define EE 4

// ws layout (4-byte units):
//  [8..10]     A,B,C LN1-collapse scalars
//  [16 ..143]  K0[e][d]   [144..271] V0[e][d]
//  [512..66047]  XNS[b][s][n]
//  ints at WS_SPI: SP[b][p] (4096), OFF[b][e] (64)
//  WS_WT: weight image:
//    [0,2048) WoT | [2048,6144) W1T | [6144,10240) W2T 2 planes
//    [10240,11392) PQR f32 (3 mats x 4 e x {P[32],Q[32],R[32]})
#define WS_K0 16
#define WS_V0 144
#define WS_XNS 512
#define WS_SPI (WS_XNS + BB*SS*NCH)          // 66048
#define WS_WT  (WS_SPI + BB*SS + 64)         // 70208

#define PRE 0.51006977f   // (1/sqrt(8)) * log2(e)

typedef __fp16 hv2 __attribute__((ext_vector_type(2)));

__device__ __forceinline__ unsigned pkh2(float a, float b) {
  hv2 r = __builtin_amdgcn_cvt_pkrtz(a, b);
  unsigned u; __builtin_memcpy(&u, &r, 4);
  return u;
}
__device__ __forceinline__ float fd2(unsigned a, unsigned b, float c) {
  hv2 av, bv;
  __builtin_memcpy(&av, &a, 4);
  __builtin_memcpy(&bv, &b, 4);
  return __builtin_amdgcn_fdot2(av, bv, c, false);
}
__device__ __forceinline__ __half2 u2h2(unsigned u) {
  __half2 h; __builtin_memcpy(&h, &u, 4); return h;
}
template<int PAT>
__device__ __forceinline__ unsigned qdpp(unsigned v) {
  return (unsigned)__builtin_amdgcn_mov_dpp((int)v, PAT, 0xF, 0xF, true);
}
template<int PAT>
__device__ __forceinline__ float qdppf(float v) {
  return __uint_as_float(qdpp<PAT>(__float_as_uint(v)));
}

// ---------------------------------------------------------------------------
// Kernel 1 (1024 thr): decomp (blocks 0..255), prep (256..271),
// weight-image convert (272..274), LN1-collapse PQR/ABC (275).  [= R12]
// ---------------------------------------------------------------------------
__launch_bounds__(1024)
__global__ void decomp_prep_kernel(const float* __restrict__ x,
                                   const float* __restrict__ ox,
                                   const float* __restrict__ sW,
                                   const float* __restrict__ sb,
                                   const float* __restrict__ g1,
                                   const float* __restrict__ bb1,
                                   const float* __restrict__ Wq,
                                   const float* __restrict__ Wk,
                                   const float* __restrict__ Wv,
                                   const float* __restrict__ Wo,
                                   const float* __restrict__ W1,
                                   const float* __restrict__ W2,
                                   float* __restrict__ ws) {
  const int t = threadIdx.x;  // 1024
  if (blockIdx.x < 256) {
    const int b = blockIdx.x / NCH;
    const int c = blockIdx.x % NCH;
    __shared__ float xs[SS];
    __shared__ float prr[1024], pii[1024];
    __shared__ float amp[129];
    __shared__ float2 YY[129];
    __shared__ float sth;
    if (t < SS) xs[t] = x[(b*SS + t)*CC + c];
    __syncthreads();
    const float TH0 = 0.024543692606170259f;  // 2*pi/256
    {
      const int f = (t & 127) + 1;
      const int chunk = t >> 7;
      const int s0 = chunk * 32;
      const int ph0 = (f * s0) & 255;
      float si, cr; sincosf(TH0*(float)ph0, &si, &cr);
      float s1, c1; sincosf(TH0*(float)f, &s1, &c1);
      float xr = 0.f, xi = 0.f;
      #pragma unroll 4
      for (int k = 0; k < 32; ++k) {
        float xvv = xs[s0 + k];
        xr += xvv * cr;
        xi -= xvv * si;
        float nc = cr*c1 - si*s1;
        si = si*c1 + cr*s1;
        cr = nc;
      }
      prr[t] = xr; pii[t] = xi;
    }
    __syncthreads();
    if (t < 128) {
      float xr = 0.f, xi = 0.f;
      #pragma unroll
      for (int k2 = 0; k2 < 8; ++k2) { xr += prr[t + 128*k2]; xi += pii[t + 128*k2]; }
      prr[t] = xr; pii[t] = xi;
      amp[t+1] = sqrtf(xr*xr + xi*xi);
    }
    __syncthreads();
    if (t < 64) {   // wave 0: top-4 knockout
      float a0 = amp[t+1], a1 = amp[t+65];
      int i0 = t+1, i1 = t+65;
      float th = -1e30f;
      for (int r = 0; r < 4; ++r) {
        float mv = (a0 > a1) ? a0 : a1;
        int   mi = (a0 > a1) ? i0 : i1;
        for (int off = 32; off > 0; off >>= 1) {
          float ov = __shfl_xor(mv, off);
          int   oi = __shfl_xor(mi, off);
          if (ov > mv || (ov == mv && oi < mi)) { mv = ov; mi = oi; }
        }
        th = mv;
        if (mi == i0) a0 = -1e30f;
        if (mi == i1) a1 = -1e30f;
      }
      if (t == 0) sth = th;
    }
    __syncthreads();
    if (t < 128) {
      const int f = t + 1;
      float wgt = (amp[f] >= sth) ? ((f == 128) ? 1.0f : 2.0f) * (1.0f/256.0f) : 0.0f;
      YY[f] = make_float2(wgt * prr[t], wgt * pii[t]);
    }
    __syncthreads();
    {
      const int s = t & 255;
      const int fc = t >> 8;
      const int f0 = 1 + fc*32;
      const int ph0 = (s * f0) & 255;
      float si, cr; sincosf(TH0*(float)ph0, &si, &cr);
      float s1, c1; sincosf(TH0*(float)s, &s1, &c1);
      float acc = 0.f;
      #pragma unroll 4
      for (int k = 0; k < 32; ++k) {
        float2 y = YY[f0 + k];
        acc += y.x*cr - y.y*si;
        float nc = cr*c1 - si*s1;
        si = si*c1 + cr*s1;
        cr = nc;
      }
      prr[t] = acc;
    }
    __syncthreads();
    if (t < 256) {
      float season = prr[t] + prr[t+256] + prr[t+512] + prr[t+768];
      float s4 = 0.f, s8 = 0.f, s12 = 0.f;
      #pragma unroll
      for (int j = 0; j < 4; ++j)  { int p = t + j - 1; p = p < 0 ? 0 : (p > SS-1 ? SS-1 : p); s4  += xs[p]; }
      #pragma unroll
      for (int j = 0; j < 8; ++j)  { int p = t + j - 3; p = p < 0 ? 0 : (p > SS-1 ? SS-1 : p); s8  += xs[p]; }
      #pragma unroll
      for (int j = 0; j < 12; ++j) { int p = t + j - 5; p = p < 0 ? 0 : (p > SS-1 ? SS-1 : p); s12 += xs[p]; }
      float trend = (s4 * 0.25f + s8 * 0.125f + s12 * (1.0f/12.0f)) * (1.0f/3.0f);
      ws[WS_XNS + (b*SS + t)*NCH + c] = xs[t] + season + trend;
    }
  } else if (blockIdx.x < 272) {
    const int b = blockIdx.x - 256;
    __shared__ float red[32];
    __shared__ int asg[SS];
    __shared__ int cnt[EE];
    __shared__ float z0[EE*DD];
    float mn = 3e38f, mx = -3e38f;
    #pragma unroll
    for (int k = 0; k < 4; ++k) {
      float v = ox[(t + k*1024)*2 + 1];
      mn = fminf(mn, v); mx = fmaxf(mx, v);
    }
    for (int off = 32; off > 0; off >>= 1) {
      mn = fminf(mn, __shfl_xor(mn, off));
      mx = fmaxf(mx, __shfl_xor(mx, off));
    }
    if ((t & 63) == 0) { red[(t>>6)*2] = mn; red[(t>>6)*2+1] = mx; }
    __syncthreads();
    mn = red[0]; mx = red[1];
    #pragma unroll
    for (int w = 1; w < 16; ++w) { mn = fminf(mn, red[w*2]); mx = fmaxf(mx, red[w*2+1]); }
    const float step = (mx - mn) * 0.25f;
    const float e1 = mn + step, e2 = mn + 2.f*step, e3 = mn + 3.f*step;
    if (t < 256) {
      float sc = ox[(b*SS + t)*2 + 1];
      asg[t] = (sc >= e1) + (sc >= e2) + (sc >= e3);
    }
    __syncthreads();
    if (t < EE) {
      int c = 0;
      for (int s2 = 0; s2 < SS; ++s2) c += (asg[s2] == t);
      cnt[t] = c;
    }
    __syncthreads();
    int* SPw  = (int*)ws + WS_SPI;
    int* OFFw = SPw + BB*SS;
    if (t < EE) {
      int off = 0;
      for (int i = 0; i < t; ++i) off += cnt[i];
      OFFw[b*EE + t] = off;
      int kp = off;
      for (int s2 = 0; s2 < SS; ++s2) if (asg[s2] == t) SPw[b*SS + (kp++)] = s2;
    }
    if (t < 128) {
      int ee = t >> 5, d = t & 31;
      float m = 0.f;
      for (int i = 0; i < DD; ++i) m += sb[i];
      m *= (1.0f/DD);
      float var = 0.f;
      for (int i = 0; i < DD; ++i) { float df = sb[i]-m; var += df*df; }
      var *= (1.0f/DD);
      float rs = rsqrtf(var + 1e-5f);
      z0[ee*DD + d] = (sb[d]-m)*rs*g1[ee*DD+d] + bb1[ee*DD+d];
    }
    __syncthreads();
    if (b == 0 && t < 128) {
      int ee = t >> 5, d = t & 31;
      float k0 = 0.f, v0 = 0.f;
      for (int i = 0; i < DD; ++i) {
        float zz = z0[ee*DD + i];
        k0 += zz * Wk[ee*DD*DD + i*DD + d];
        v0 += zz * Wv[ee*DD*DD + i*DD + d];
      }
      ws[WS_K0 + ee*DD + d] = k0;
      ws[WS_V0 + ee*DD + d] = v0;
    }
  } else if (blockIdx.x < 275) {
    // weight-image converters: 3 blocks x 4096 slots cover [0, 10240)
    unsigned* img = (unsigned*)ws + WS_WT;
    const int base_u = (blockIdx.x - 272)*4096;
    #pragma unroll
    for (int i = 0; i < 4; ++i) {
      int u = base_u + i*1024 + t;
      if (u < 10240) {
        unsigned val;
        if (u < 2048) {                  // WoT
          int row = u >> 4, ip = u & 15;
          int e = row >> 5, qq = row & 31;
          int d = (qq & 3)*8 + (qq >> 2);
          const float* src = Wo + e*1024 + d;
          val = pkh2(src[ip*64], src[ip*64 + 32]);
        } else if (u < 6144) {           // W1T
          int r = u - 2048;
          int row = r >> 4, ip = r & 15;
          int e = row >> 6, qq = row & 63;
          int j = (qq & 3)*16 + (qq >> 2);
          const float* src = W1 + e*2048 + j;
          val = pkh2(src[ip*128], src[ip*128 + 64]);
        } else {                         // W2T (two planes)
          int r = u - 6144;
          int a = r >> 11, rr = r & 2047;
          int row = rr >> 4, ip = rr & 15;
          int e = row >> 5, qq = row & 31;
          int d = (qq & 3)*8 + (qq >> 2);
          int jp = a*16 + ip;
          const float* src = W2 + e*2048 + d;
          val = pkh2(src[2*jp*32], src[(2*jp+1)*32]);
        }
        img[u] = val;
      }
    }
  } else {
    // block 275: LN1-collapse precompute.
    __shared__ float s_a[DD], s_c[DD];
    if (t < DD) { s_a[t] = sW[t]; s_c[t] = sb[t]; }
    __syncthreads();
    if (t == 0) {
      float mW = 0.f, mb = 0.f;
      for (int d = 0; d < DD; ++d) { mW += s_a[d]; mb += s_c[d]; }
      mW *= (1.0f/DD); mb *= (1.0f/DD);
      float A = 0.f, Bv = 0.f, Cv = 0.f;
      for (int d = 0; d < DD; ++d) {
        float a = s_a[d] - mW, c = s_c[d] - mb;
        s_a[d] = a; s_c[d] = c;
        A += a*a; Bv += a*c; Cv += c*c;
      }
      ws[8]  = A  * (1.0f/DD);
      ws[9]  = Bv * (1.0f/DD);
      ws[10] = Cv * (1.0f/DD);
    }
    __syncthreads();
    if (t < 384) {
      const int m = t >> 7, r = t & 127, e = r >> 5, j = r & 31;
      const float* Wm = (m == 0) ? Wq : (m == 1) ? Wk : Wv;
      float pp = 0.f, qq = 0.f, rr = 0.f;
      for (int d = 0; d < DD; ++d) {
        float w  = Wm[e*DD*DD + d*DD + j];
        float gg = g1[e*DD + d];
        pp += s_a[d]*gg*w;
        qq += s_c[d]*gg*w;
        rr += bb1[e*DD + d]*w;
      }
      float* pqr = ws + WS_WT + 10240;   // f32 tail of image region
      const int base = (m*EE + e)*96 + j;
      pqr[base]      = pp;
      pqr[base + 32] = qq;
      pqr[base + 64] = rr;
    }
  }
}

// ---------------------------------------------------------------------------
// Kernel 2 (R15): grid 512 = (b,n,half), 512 thr, LDS 77KB -> 2 blocks/CU.
// R14 falsified the LDS-instruction-count model (halving attn reads moved
// nothing); R13 showed ~3x above issue floor => latency-stall-bound with one
// lockstep 16-wave block/CU. R15 keeps R12's inner code byte-identical but
// splits each (b,n) into TWO independent 512-thr blocks (own barriers, own
// phase timing -> one block's attention overlaps the other's FFN; tail
// halves). Each block owns 128 positions; each quad computes kv for sorted
// positions 2q,2q+1 (QKV is collapsed/cheap) so both blocks stage all 256.
// ---------------------------------------------------------------------------
__launch_bounds__(512, 4)
__global__ void fused_kernel(const float* __restrict__ ws,
    const float* __restrict__ g1, const float* __restrict__ bb1,
    const float* __restrict__ sW, const float* __restrict__ sb,
    const float* __restrict__ g2, const float* __restrict__ bb2,
    const float* __restrict__ b1, const float* __restrict__ b2,
    float* __restrict__ out) {
  const int blk = blockIdx.x;
  const int half = blk & 1;
  const int n = (blk >> 1) & 15;
  const int b = blk >> 5;
  const int t = threadIdx.x;      // 0..511
  const int qd = t >> 2;          // quad 0..127
  const int hh = t & 3;
  const int p  = half*128 + qd;   // own sorted position
  const int pa = qd*2, pb = qd*2 + 1;   // kv-staging positions (cover 0..255)
  __shared__ unsigned lds[19712];   // [0,8192) kv | [8192,19712) image+PQR (45KB)
  unsigned* wl = lds + 8192;

  // async-stage image+PQR (45 x 1KB chunks; 8 waves x <=6)
  {
    const unsigned* img = (const unsigned*)ws + WS_WT;
    const int wv = t >> 6;
    const int ln = t & 63;
    #pragma unroll
    for (int i = 0; i < 6; ++i) {
      const int ch = wv*6 + i;
      if (ch < 45) {
        __builtin_amdgcn_global_load_lds(
            (const __attribute__((address_space(1))) unsigned*)(img + ch*256 + ln*4),
            (__attribute__((address_space(3))) unsigned*)(wl + ch*256 + ln*4),
            16, 0, 0);
      }
    }
  }

  const int* SP  = (const int*)ws + WS_SPI;
  const int* OFF = SP + BB*SS;
  const int o1 = OFF[b*4+1], o2v = OFF[b*4+2], o3 = OFF[b*4+3];
  const int e = (p >= o1) + (p >= o2v) + (p >= o3);
  const int beg = (e==0) ? 0  : ((e==1) ? o1 : ((e==2) ? o2v : o3));
  const int end = (e==0) ? o1 : ((e==1) ? o2v : ((e==2) ? o3 : SS));
  const int ea = (pa >= o1) + (pa >= o2v) + (pa >= o3);
  const int eb = (pb >= o1) + (pb >= o2v) + (pb >= o3);
  const int s  = SP[b*SS + p];
  const int sa = SP[b*SS + pa];
  const int sbp = SP[b*SS + pb];
  const float xv  = ws[WS_XNS + (b*SS + s)*NCH + n];
  const float xva = ws[WS_XNS + (b*SS + sa)*NCH + n];
  const float xvb = ws[WS_XNS + (b*SS + sbp)*NCH + n];

  // LN1 collapse: var is a quadratic in xv
  const float Ac = ws[8], Bc = ws[9], Cc = ws[10];
  const float rsO = rsqrtf(fmaf(xv,  fmaf(Ac, xv,  Bc + Bc), Cc) + 1e-5f);
  const float rsA = rsqrtf(fmaf(xva, fmaf(Ac, xva, Bc + Bc), Cc) + 1e-5f);
  const float rsB = rsqrtf(fmaf(xvb, fmaf(Ac, xvb, Bc + Bc), Cc) + 1e-5f);
  const float alO = rsO*xv,  beO = rsO;
  const float alA = rsA*xva, beA = rsA;
  const float alB = rsB*xvb, beB = rsB;
  __syncthreads();   // barrier 1: image+PQR staged (vmcnt drained)

  const float* pqr = (const float*)(wl + 10240);

  // own q (mat 0, expert e)
  float q[DH];
  {
    const float* bp = &pqr[(0*EE + e)*96 + hh*DH];
    const float4 P0 = *(const float4*)(bp);
    const float4 P1 = *(const float4*)(bp + 4);
    const float4 Q0 = *(const float4*)(bp + 32);
    const float4 Q1 = *(const float4*)(bp + 36);
    const float4 R0 = *(const float4*)(bp + 64);
    const float4 R1 = *(const float4*)(bp + 68);
    q[0] = fmaf(alO, P0.x, fmaf(beO, Q0.x, R0.x));
    q[1] = fmaf(alO, P0.y, fmaf(beO, Q0.y, R0.y));
    q[2] = fmaf(alO, P0.z, fmaf(beO, Q0.z, R0.z));
    q[3] = fmaf(alO, P0.w, fmaf(beO, Q0.w, R0.w));
    q[4] = fmaf(alO, P1.x, fmaf(beO, Q1.x, R1.x));
    q[5] = fmaf(alO, P1.y, fmaf(beO, Q1.y, R1.y));
    q[6] = fmaf(alO, P1.z, fmaf(beO, Q1.z, R1.z));
    q[7] = fmaf(alO, P1.w, fmaf(beO, Q1.w, R1.w));
    #pragma unroll
    for (int dd = 0; dd < DH; ++dd) q[dd] *= PRE;
  }
  // k/v for staging positions pa, pb (mats 1,2; experts ea, eb)
  #pragma unroll
  for (int u = 0; u < 2; ++u) {
    const int ex = (u == 0) ? ea : eb;
    const float al = (u == 0) ? alA : alB;
    const float be = (u == 0) ? beA : beB;
    const int px = (u == 0) ? pa : pb;
    float kk[DH], vv[DH];
    #pragma unroll
    for (int m = 1; m < 3; ++m) {
      const float* bp = &pqr[(m*EE + ex)*96 + hh*DH];
      const float4 P0 = *(const float4*)(bp);
      const float4 P1 = *(const float4*)(bp + 4);
      const float4 Q0 = *(const float4*)(bp + 32);
      const float4 Q1 = *(const float4*)(bp + 36);
      const float4 R0 = *(const float4*)(bp + 64);
      const float4 R1 = *(const float4*)(bp + 68);
      float* dst = (m == 1) ? kk : vv;
      dst[0] = fmaf(al, P0.x, fmaf(be, Q0.x, R0.x));
      dst[1] = fmaf(al, P0.y, fmaf(be, Q0.y, R0.y));
      dst[2] = fmaf(al, P0.z, fmaf(be, Q0.z, R0.z));
      dst[3] = fmaf(al, P0.w, fmaf(be, Q0.w, R0.w));
      dst[4] = fmaf(al, P1.x, fmaf(be, Q1.x, R1.x));
      dst[5] = fmaf(al, P1.y, fmaf(be, Q1.y, R1.y));
      dst[6] = fmaf(al, P1.z, fmaf(be, Q1.z, R1.z));
      dst[7] = fmaf(al, P1.w, fmaf(be, Q1.w, R1.w));
    }
    *(uint4*)&lds[px*32 + hh*8]     = make_uint4(pkh2(kk[0],kk[1]), pkh2(kk[2],kk[3]),
                                                 pkh2(kk[4],kk[5]), pkh2(kk[6],kk[7]));
    *(uint4*)&lds[px*32 + hh*8 + 4] = make_uint4(pkh2(vv[0],vv[1]), pkh2(vv[2],vv[3]),
                                                 pkh2(vv[4],vv[5]), pkh2(vv[6],vv[7]));
  }
  unsigned qp2[4];
  #pragma unroll
  for (int i = 0; i < 4; ++i) qp2[i] = pkh2(q[2*i], q[2*i+1]);
  float s0 = 0.f;
  #pragma unroll
  for (int d = 0; d < DH; ++d) s0 += q[d] * ws[WS_K0 + e*DD + hh*DH + d];
  __syncthreads();   // barrier 2: kv staged — LAST barrier

  // attention: o accumulated as packed f16 pairs (v_pk_fma_f16)  [= R12]
  float wsum = 0.f;
  __half2 o2[4];
  #pragma unroll
  for (int i = 0; i < 4; ++i) o2[i] = u2h2(0u);
  int jk = beg;
  for (; jk + 1 < end; jk += 2) {
    uint4 ku0 = *(const uint4*)&lds[jk*32 + hh*8];
    uint4 vu0 = *(const uint4*)&lds[jk*32 + hh*8 + 4];
    uint4 ku1 = *(const uint4*)&lds[(jk+1)*32 + hh*8];
    uint4 vu1 = *(const uint4*)&lds[(jk+1)*32 + hh*8 + 4];
    float a0 = 0.f, a1 = 0.f;
    a0 = fd2(qp2[0], ku0.x, a0); a0 = fd2(qp2[1], ku0.y, a0);
    a0 = fd2(qp2[2], ku0.z, a0); a0 = fd2(qp2[3], ku0.w, a0);
    a1 = fd2(qp2[0], ku1.x, a1); a1 = fd2(qp2[1], ku1.y, a1);
    a1 = fd2(qp2[2], ku1.z, a1); a1 = fd2(qp2[3], ku1.w, a1);
    float w0f = __builtin_amdgcn_exp2f(a0);
    float w1f = __builtin_amdgcn_exp2f(a1);
    wsum += w0f + w1f;
    __half2 w20 = u2h2(pkh2(w0f, w0f));
    __half2 w21 = u2h2(pkh2(w1f, w1f));
    o2[0] = __hfma2(w20, u2h2(vu0.x), o2[0]);
    o2[1] = __hfma2(w20, u2h2(vu0.y), o2[1]);
    o2[2] = __hfma2(w20, u2h2(vu0.z), o2[2]);
    o2[3] = __hfma2(w20, u2h2(vu0.w), o2[3]);
    o2[0] = __hfma2(w21, u2h2(vu1.x), o2[0]);
    o2[1] = __hfma2(w21, u2h2(vu1.y), o2[1]);
    o2[2] = __hfma2(w21, u2h2(vu1.z), o2[2]);
    o2[3] = __hfma2(w21, u2h2(vu1.w), o2[3]);
  }
  if (jk < end) {
    uint4 ku = *(const uint4*)&lds[jk*32 + hh*8];
    uint4 vu = *(const uint4*)&lds[jk*32 + hh*8 + 4];
    float a = 0.f;
    a = fd2(qp2[0], ku.x, a); a = fd2(qp2[1], ku.y, a);
    a = fd2(qp2[2], ku.z, a); a = fd2(qp2[3], ku.w, a);
    float wf = __builtin_amdgcn_exp2f(a);
    wsum += wf;
    __half2 w2 = u2h2(pkh2(wf, wf));
    o2[0] = __hfma2(w2, u2h2(vu.x), o2[0]);
    o2[1] = __hfma2(w2, u2h2(vu.y), o2[1]);
    o2[2] = __hfma2(w2, u2h2(vu.z), o2[2]);
    o2[3] = __hfma2(w2, u2h2(vu.w), o2[3]);
  }
  // off-expert keys: constant score s0, constant value v0
  float o[DH];
  #pragma unroll
  for (int i = 0; i < 4; ++i) {
    o[2*i]   = __low2float(o2[i]);
    o[2*i+1] = __high2float(o2[i]);
  }
  const int nmis = SS - (end - beg);
  float w0 = (float)nmis * __builtin_amdgcn_exp2f(s0);
  wsum += w0;
  #pragma unroll
  for (int d = 0; d < DH; ++d) o[d] += w0 * ws[WS_V0 + e*DD + hh*DH + d];
  float inv = 1.0f / wsum;
  #pragma unroll
  for (int d = 0; d < DH; ++d) o[d] *= inv;

  // ---- o gather via DPP quad broadcast (no barrier, no LDS) ----
  unsigned oq[4];
  #pragma unroll
  for (int j = 0; j < 4; ++j) oq[j] = pkh2(o[2*j], o[2*j+1]);
  unsigned ovp[16];
  #pragma unroll
  for (int j = 0; j < 4; ++j) {
    ovp[j]    = qdpp<0x00>(oq[j]);
    ovp[4+j]  = qdpp<0x55>(oq[j]);
    ovp[8+j]  = qdpp<0xAA>(oq[j]);
    ovp[12+j] = qdpp<0xFF>(oq[j]);
  }

  // Wo + residual: acc[dd] = h2 at dim hh*8+dd
  float acc[DH];
  #pragma unroll
  for (int dd = 0; dd < DH; ++dd) {
    int d = hh*DH + dd;
    const uint4* row = (const uint4*)&wl[(e*32 + dd*4 + hh)*16];
    float a = xv * sW[d] + sb[d];
    #pragma unroll
    for (int g4 = 0; g4 < 4; ++g4) {
      uint4 w4 = row[g4];
      a = fd2(ovp[4*g4+0], w4.x, a); a = fd2(ovp[4*g4+1], w4.y, a);
      a = fd2(ovp[4*g4+2], w4.z, a); a = fd2(ovp[4*g4+3], w4.w, a);
    }
    acc[dd] = a;
  }

  // ---- LN2 via quad-sum DPP reductions ----
  float ssum = 0.f;
  #pragma unroll
  for (int dd = 0; dd < DH; ++dd) ssum += acc[dd];
  ssum += qdppf<0xB1>(ssum);
  ssum += qdppf<0x4E>(ssum);
  float m2 = ssum * (1.0f/DD);
  float vs = 0.f;
  #pragma unroll
  for (int dd = 0; dd < DH; ++dd) { float df = acc[dd]-m2; vs += df*df; }
  vs += qdppf<0xB1>(vs);
  vs += qdppf<0x4E>(vs);
  float rs2 = rsqrtf(vs * (1.0f/DD) + 1e-5f);
  unsigned zq[4];
  #pragma unroll
  for (int j = 0; j < 4; ++j) {
    int d = hh*DH + 2*j;
    float za = (acc[2*j]  -m2)*rs2*g2[e*DD+d]   + bb2[e*DD+d];
    float zb = (acc[2*j+1]-m2)*rs2*g2[e*DD+d+1] + bb2[e*DD+d+1];
    zq[j] = pkh2(za, zb);
  }
  unsigned zp2[16];
  #pragma unroll
  for (int j = 0; j < 4; ++j) {
    zp2[j]    = qdpp<0x00>(zq[j]);
    zp2[4+j]  = qdpp<0x55>(zq[j]);
    zp2[8+j]  = qdpp<0xAA>(zq[j]);
    zp2[12+j] = qdpp<0xFF>(zq[j]);
  }

  // FFN1: f[hh*16 .. +16)
  float f[16];
  #pragma unroll
  for (int jj = 0; jj < 16; ++jj) {
    const uint4* row = (const uint4*)&wl[2048 + (e*64 + jj*4 + hh)*16];
    float a = b1[e*DFFN + hh*16 + jj];
    #pragma unroll
    for (int g4 = 0; g4 < 4; ++g4) {
      uint4 w4 = row[g4];
      a = fd2(zp2[4*g4+0], w4.x, a); a = fd2(zp2[4*g4+1], w4.y, a);
      a = fd2(zp2[4*g4+2], w4.z, a); a = fd2(zp2[4*g4+3], w4.w, a);
    }
    f[jj] = fmaxf(a, 0.0f);
  }
  // ---- f gather via DPP quad broadcast ----
  unsigned fq[8];
  #pragma unroll
  for (int j = 0; j < 8; ++j) fq[j] = pkh2(f[2*j], f[2*j+1]);
  unsigned fu[32];
  #pragma unroll
  for (int j = 0; j < 8; ++j) {
    fu[j]    = qdpp<0x00>(fq[j]);
    fu[8+j]  = qdpp<0x55>(fq[j]);
    fu[16+j] = qdpp<0xAA>(fq[j]);
    fu[24+j] = qdpp<0xFF>(fq[j]);
  }

  // FFN2 + residual + b2
  float acc2[DH];
  #pragma unroll
  for (int dd = 0; dd < DH; ++dd) {
    int d = hh*DH + dd;
    const int row16 = (e*32 + dd*4 + hh)*16;
    float a = acc[dd] + b2[e*DD + d];
    #pragma unroll
    for (int g4 = 0; g4 < 8; ++g4) {
      const int plane = (g4 >> 2);
      uint4 w4 = *(const uint4*)&wl[6144 + plane*2048 + row16 + 4*(g4 & 3)];
      a = fd2(fu[4*g4+0], w4.x, a); a = fd2(fu[4*g4+1], w4.y, a);
      a = fd2(fu[4*g4+2], w4.z, a); a = fd2(fu[4*g4+3], w4.w, a);
    }
    acc2[dd] = a;
  }
  float* op = out + ((size_t)((b*SS + s)*NCH + n))*DD + hh*DH;
  *(float4*)(op)     = make_float4(acc2[0], acc2[1], acc2[2], acc2[3]);
  *(float4*)(op + 4) = make_float4(acc2[4], acc2[5], acc2[6], acc2[7]);
}

// ---------------------------------------------------------------------------
extern "C" void kernel_launch(void* const* d_in, const int* in_sizes, int n_in,
                              void* d_out, int out_size, void* d_ws, size_t ws_size,
                              hipStream_t stream) {
  (void)in_sizes; (void)n_in; (void)out_size; (void)ws_size;
  const float* x   = (const float*)d_in[0];
  const float* ox  = (const float*)d_in[1];
  const float* sW  = (const float*)d_in[2];
  const float* sb  = (const float*)d_in[3];
  const float* Wq  = (const float*)d_in[4];
  const float* Wk  = (const float*)d_in[5];
  const float* Wv  = (const float*)d_in[6];
  const float* Wo  = (const float*)d_in[7];
  const float* g1  = (const float*)d_in[8];
  const float* b1n = (const float*)d_in[9];
  const float* g2  = (const float*)d_in[10];
  const float* b2n = (const float*)d_in[11];
  const float* W1  = (const float*)d_in[12];
  const float* bf1 = (const float*)d_in[13];
  const float* W2  = (const float*)d_in[14];
  const float* bf2 = (const float*)d_in[15];
  float* out = (float*)d_out;
  float* ws  = (float*)d_ws;

  decomp_prep_kernel<<<276, 1024, 0, stream>>>(x, ox, sW, sb, g1, b1n,
                                               Wq, Wk, Wv, Wo, W1, W2, ws);
  fused_kernel<<<BB*NCH*2, 512, 0, stream>>>(ws, g1, b1n, sW, sb, g2, b2n,
                                             bf1, bf2, out);
}